// Round 1
// baseline (141.615 us; speedup 1.0000x reference)
//
#include <hip/hip_runtime.h>

typedef __attribute__((ext_vector_type(8))) short bf16x8;
typedef __attribute__((ext_vector_type(4))) float f32x4;
typedef __attribute__((ext_vector_type(4))) unsigned int u32x4;

#define NB 64
#define SQ 198
#define SKV 206
#define DM 768
#define NH 12
#define NROWS (NB * SKV)   // 13184
#define NCOL 2304          // Q | K | V columns

static __device__ __forceinline__ unsigned short f2b(float f) {
  union { float f; unsigned u; } v; v.f = f;
  unsigned r = v.u + 0x7FFFu + ((v.u >> 16) & 1u);
  return (unsigned short)(r >> 16);
}

// ---------- build bf16 Xkv[13184][768]: rows = hidden(198) + memory(8) per batch ----------
__global__ __launch_bounds__(256) void k_conv_x(const float* __restrict__ hid,
                                                const float* __restrict__ mem,
                                                unsigned short* __restrict__ xkv) {
  int idx = (blockIdx.x * 256 + threadIdx.x) * 8;   // element index, < 10,125,312
  int r = idx / DM;
  int c = idx - r * DM;
  int b = r / SKV, s = r - b * SKV;
  const float* src = (s < SQ) ? (hid + (b * SQ + s) * DM + c)
                              : (mem + (s - SQ) * DM + c);
  float4 v0 = ((const float4*)src)[0];
  float4 v1 = ((const float4*)src)[1];
  unsigned w0 = f2b(v0.x) | ((unsigned)f2b(v0.y) << 16);
  unsigned w1 = f2b(v0.z) | ((unsigned)f2b(v0.w) << 16);
  unsigned w2 = f2b(v1.x) | ((unsigned)f2b(v1.y) << 16);
  unsigned w3 = f2b(v1.z) | ((unsigned)f2b(v1.w) << 16);
  u32x4 o = {w0, w1, w2, w3};
  *(u32x4*)(xkv + idx) = o;
}

// ---------- transpose W -> bf16 Wt[w][n][k] so GEMM B-frags are k-contiguous ----------
__global__ __launch_bounds__(256) void k_conv_w(const float* __restrict__ Wq,
                                                const float* __restrict__ Wk,
                                                const float* __restrict__ Wv,
                                                unsigned short* __restrict__ wt) {
  __shared__ float L[64][65];
  int w = blockIdx.z;
  int n0 = blockIdx.x * 64, k0 = blockIdx.y * 64;
  const float* W = (w == 0) ? Wq : (w == 1) ? Wk : Wv;
  int tid = threadIdx.x;
#pragma unroll
  for (int i = 0; i < 16; ++i) {
    int idx = i * 256 + tid;
    int lr = idx >> 6, lc = idx & 63;
    L[lr][lc] = W[(k0 + lr) * DM + n0 + lc];
  }
  __syncthreads();
  unsigned short* dst = wt + w * DM * DM;
#pragma unroll
  for (int o = 0; o < 2; ++o) {
    int gi = o * 256 + tid;
    int rn = gi >> 3, g = gi & 7;
    unsigned wrd[4];
#pragma unroll
    for (int jj = 0; jj < 4; ++jj) {
      float f0 = L[g * 8 + jj * 2 + 0][rn];
      float f1 = L[g * 8 + jj * 2 + 1][rn];
      wrd[jj] = f2b(f0) | ((unsigned)f2b(f1) << 16);
    }
    u32x4 o4 = {wrd[0], wrd[1], wrd[2], wrd[3]};
    *(u32x4*)(dst + (n0 + rn) * DM + k0 + g * 8) = o4;
  }
}

// ---------- fused QKV GEMM: C[13184][2304] = Xkv @ [Wq|Wk|Wv] + bias, bf16 out ----------
// 128x128 tile, BK=64, 4 waves (each 64x64), XOR-swizzled LDS, reg-staged.
__global__ __launch_bounds__(256, 2) void k_gemm(const unsigned short* __restrict__ xkv,
                                                 const unsigned short* __restrict__ wt,
                                                 const float* __restrict__ bq,
                                                 const float* __restrict__ bk,
                                                 const float* __restrict__ bv,
                                                 unsigned short* __restrict__ cout) {
  __shared__ __align__(16) unsigned char smem[34816]; // A[0,16K) B[16K,32K); epilogue C[0,34816)
  int nt = blockIdx.x, mt = blockIdx.y;
  int row0 = mt * 128, col0 = nt * 128;
  int w = nt / 6;                 // 0=Q 1=K 2=V
  int colw0 = col0 - w * 768;
  int tid = threadIdx.x, lane = tid & 63, wid = tid >> 6;
  int wr = wid >> 1, wc = wid & 1;
  const unsigned short* wbase = wt + w * DM * DM;

  f32x4 zero = {0.f, 0.f, 0.f, 0.f};
  f32x4 acc[4][4];
#pragma unroll
  for (int i = 0; i < 4; ++i)
#pragma unroll
    for (int j = 0; j < 4; ++j) acc[i][j] = zero;

  int arow[4], ag[4], aoff[4];
#pragma unroll
  for (int j = 0; j < 4; ++j) {
    int sidx = j * 256 + tid;     // 16B granule id, tile = 1024 granules
    int r = sidx >> 3, g = sidx & 7;
    arow[j] = r;
    ag[j] = g;
    aoff[j] = (r * 128 + g * 16) ^ ((r & 7) << 4);   // swizzled LDS byte
  }

  for (int ks = 0; ks < 12; ++ks) {
    int k0 = ks * 64;
    bf16x8 av[4], bvv[4];
#pragma unroll
    for (int j = 0; j < 4; ++j) {
      av[j]  = *(const bf16x8*)(xkv   + (row0 + arow[j])  * DM + k0 + ag[j] * 8);
      bvv[j] = *(const bf16x8*)(wbase + (colw0 + arow[j]) * DM + k0 + ag[j] * 8);
    }
    __syncthreads();              // previous compute done reading LDS
#pragma unroll
    for (int j = 0; j < 4; ++j) {
      *(bf16x8*)(smem + aoff[j]) = av[j];
      *(bf16x8*)(smem + 16384 + aoff[j]) = bvv[j];
    }
    __syncthreads();              // tile staged
#pragma unroll
    for (int kk = 0; kk < 2; ++kk) {
      bf16x8 a[4], b[4];
      int kbyte = (kk * 32 + ((lane >> 4) * 8)) * 2;
#pragma unroll
      for (int mi = 0; mi < 4; ++mi) {
        int rr = wr * 64 + mi * 16 + (lane & 15);
        a[mi] = *(const bf16x8*)(smem + rr * 128 + (kbyte ^ ((rr & 7) << 4)));
      }
#pragma unroll
      for (int ni = 0; ni < 4; ++ni) {
        int rr = wc * 64 + ni * 16 + (lane & 15);
        b[ni] = *(const bf16x8*)(smem + 16384 + rr * 128 + (kbyte ^ ((rr & 7) << 4)));
      }
#pragma unroll
      for (int mi = 0; mi < 4; ++mi)
#pragma unroll
        for (int ni = 0; ni < 4; ++ni)
          acc[mi][ni] = __builtin_amdgcn_mfma_f32_16x16x32_bf16(a[mi], b[ni], acc[mi][ni], 0, 0, 0);
    }
  }

  const float* bias = (w == 0) ? bq : (w == 1) ? bk : bv;
  float bb[4];
#pragma unroll
  for (int ni = 0; ni < 4; ++ni) bb[ni] = bias[colw0 + wc * 64 + ni * 16 + (lane & 15)];

  __syncthreads();   // last compute done before overwriting smem with C tile
#pragma unroll
  for (int mi = 0; mi < 4; ++mi)
#pragma unroll
    for (int ni = 0; ni < 4; ++ni)
#pragma unroll
      for (int r = 0; r < 4; ++r) {
        int row = wr * 64 + mi * 16 + (lane >> 4) * 4 + r;
        int col = wc * 64 + ni * 16 + (lane & 15);
        *(unsigned short*)(smem + row * 272 + col * 2) = f2b(acc[mi][ni][r] + bb[ni]);
      }
  __syncthreads();
#pragma unroll
  for (int it = 0; it < 8; ++it) {
    int gi = it * 256 + tid;
    int row = gi >> 4, g = gi & 15;
    u32x4 v = *(const u32x4*)(smem + row * 272 + g * 16);
    *(u32x4*)(cout + (row0 + row) * NCOL + col0 + g * 8) = v;
  }
}

// ---------- attention: one block per (b,h); Sq=198 in 13 tiles of 16 rows ----------
__global__ __launch_bounds__(256, 1) void k_attn(const unsigned short* __restrict__ cqkv,
                                                 float* __restrict__ out) {
  __shared__ __align__(16) unsigned short Ksh[208 * 64];      // swizzled [key][dh]
  __shared__ __align__(16) unsigned short Vt[64 * 232];       // [dh][key], cols 206..231 zero
  __shared__ __align__(16) unsigned short Psh[4][16 * 232];   // per-wave P, cols 208..231 zero
  int bh = blockIdx.x;
  int b = bh / NH, h = bh - b * NH;
  int tid = threadIdx.x, lane = tid & 63, wid = tid >> 6;
  const unsigned short* Cb = cqkv + (b * SKV) * NCOL + h * 64;

  for (int i = tid; i < 64 * 26; i += 256) { int dh = i / 26, c = i - dh * 26; Vt[dh * 232 + 206 + c] = 0; }
  for (int i = tid; i < 4 * 16 * 24; i += 256) {
    int ww = i / 384, rem = i - ww * 384;
    int rr = rem / 24, c = rem - rr * 24;
    Psh[ww][rr * 232 + 208 + c] = 0;
  }
  for (int i = tid; i < 208 * 8; i += 256) {      // stage K (rows 206,207 duplicated->masked)
    int row = i >> 3, g = i & 7;
    int srow = (row < SKV) ? row : (SKV - 1);
    u32x4 v = *(const u32x4*)(Cb + srow * NCOL + 768 + g * 8);
    *(u32x4*)((unsigned char*)Ksh + ((row * 128 + g * 16) ^ ((row & 7) << 4))) = v;
  }
  for (int i = tid; i < 206 * 8; i += 256) {      // stage V transposed
    int key = i >> 3, g = i & 7;
    u32x4 v = *(const u32x4*)(Cb + key * NCOL + 1536 + g * 8);
    union { u32x4 v4; unsigned short e[8]; } u; u.v4 = v;
#pragma unroll
    for (int j = 0; j < 8; ++j) Vt[(g * 8 + j) * 232 + key] = u.e[j];
  }
  __syncthreads();

  const float scale = 0.125f;
  f32x4 zero = {0.f, 0.f, 0.f, 0.f};
  for (int qt = wid; qt < 13; qt += 4) {
    int qr_load = qt * 16 + (lane & 15); if (qr_load > 197) qr_load = 197;
    const unsigned short* qp = Cb + qr_load * NCOL + (lane >> 4) * 8;
    bf16x8 qa0 = *(const bf16x8*)qp;
    bf16x8 qa1 = *(const bf16x8*)(qp + 32);

    f32x4 sc[13];
#pragma unroll
    for (int nt2 = 0; nt2 < 13; ++nt2) sc[nt2] = zero;
#pragma unroll
    for (int nt2 = 0; nt2 < 13; ++nt2) {
      int key = nt2 * 16 + (lane & 15);
      int rb = key * 128, sw = (key & 7) << 4, g0 = (lane >> 4) * 16;
      bf16x8 kb0 = *(const bf16x8*)((const unsigned char*)Ksh + rb + (g0 ^ sw));
      bf16x8 kb1 = *(const bf16x8*)((const unsigned char*)Ksh + rb + ((g0 + 64) ^ sw));
      sc[nt2] = __builtin_amdgcn_mfma_f32_16x16x32_bf16(qa0, kb0, sc[nt2], 0, 0, 0);
      sc[nt2] = __builtin_amdgcn_mfma_f32_16x16x32_bf16(qa1, kb1, sc[nt2], 0, 0, 0);
    }

    int qbase = qt * 16 + (lane >> 4) * 4;
#pragma unroll
    for (int r = 0; r < 4; ++r) {
      int qr = qbase + r;
      float mx = -1e30f;
#pragma unroll
      for (int nt2 = 0; nt2 < 13; ++nt2) {
        int key = nt2 * 16 + (lane & 15);
        float s = sc[nt2][r] * scale;
        bool ok = (key < 197 || qr == 197) && (key < SKV);
        s = ok ? s : -1e30f;
        sc[nt2][r] = s;
        mx = fmaxf(mx, s);
      }
      mx = fmaxf(mx, __shfl_xor(mx, 1));
      mx = fmaxf(mx, __shfl_xor(mx, 2));
      mx = fmaxf(mx, __shfl_xor(mx, 4));
      mx = fmaxf(mx, __shfl_xor(mx, 8));
      float sum = 0.f;
#pragma unroll
      for (int nt2 = 0; nt2 < 13; ++nt2) {
        float p = __expf(sc[nt2][r] - mx);
        sc[nt2][r] = p;
        sum += p;
      }
      sum += __shfl_xor(sum, 1);
      sum += __shfl_xor(sum, 2);
      sum += __shfl_xor(sum, 4);
      sum += __shfl_xor(sum, 8);
      float inv = 1.0f / sum;
#pragma unroll
      for (int nt2 = 0; nt2 < 13; ++nt2) sc[nt2][r] *= inv;
    }

    unsigned short* P = &Psh[wid][0];
#pragma unroll
    for (int r = 0; r < 4; ++r) {
      int row = (lane >> 4) * 4 + r;
#pragma unroll
      for (int nt2 = 0; nt2 < 13; ++nt2)
        P[row * 232 + nt2 * 16 + (lane & 15)] = f2b(sc[nt2][r]);
    }

    f32x4 ctx[4];
#pragma unroll
    for (int dt = 0; dt < 4; ++dt) ctx[dt] = zero;
#pragma unroll
    for (int kt = 0; kt < 7; ++kt) {
      bf16x8 pa = *(const bf16x8*)(P + (lane & 15) * 232 + kt * 32 + (lane >> 4) * 8);
#pragma unroll
      for (int dt = 0; dt < 4; ++dt) {
        bf16x8 vb = *(const bf16x8*)(Vt + (dt * 16 + (lane & 15)) * 232 + kt * 32 + (lane >> 4) * 8);
        ctx[dt] = __builtin_amdgcn_mfma_f32_16x16x32_bf16(pa, vb, ctx[dt], 0, 0, 0);
      }
    }
#pragma unroll
    for (int dt = 0; dt < 4; ++dt)
#pragma unroll
      for (int r = 0; r < 4; ++r) {
        int qr = qbase + r;
        if (qr < SQ)
          out[(b * SQ + qr) * DM + h * 64 + dt * 16 + (lane & 15)] = ctx[dt][r];
      }
  }
}

extern "C" void kernel_launch(void* const* d_in, const int* in_sizes, int n_in,
                              void* d_out, int out_size, void* d_ws, size_t ws_size,
                              hipStream_t stream) {
  const float* hid = (const float*)d_in[0];
  const float* mem = (const float*)d_in[1];
  const float* Wq  = (const float*)d_in[2];
  const float* bq  = (const float*)d_in[3];
  const float* Wk  = (const float*)d_in[4];
  const float* bk  = (const float*)d_in[5];
  const float* Wv  = (const float*)d_in[6];
  const float* bv  = (const float*)d_in[7];
  float* out = (float*)d_out;

  // workspace layout (bf16): Xkv 10,125,312 | Wt 1,769,472 | C 30,375,936  => 84.5 MB
  unsigned short* xkv  = (unsigned short*)d_ws;
  unsigned short* wt   = xkv + NROWS * DM;
  unsigned short* cbuf = wt + 3 * DM * DM;

  k_conv_x<<<dim3(NROWS * DM / 8 / 256), 256, 0, stream>>>(hid, mem, xkv);
  k_conv_w<<<dim3(12, 12, 3), 256, 0, stream>>>(Wq, Wk, Wv, wt);
  k_gemm<<<dim3(18, 103), 256, 0, stream>>>(xkv, wt, bq, bk, bv, cbuf);
  k_attn<<<dim3(NB * NH), 256, 0, stream>>>(cbuf, out);
}

// Round 3
// 110.052 us; speedup vs baseline: 1.2868x; 1.2868x over previous
//
#include <hip/hip_runtime.h>

typedef __attribute__((ext_vector_type(8))) short bf16x8;
typedef __attribute__((ext_vector_type(4))) float f32x4;
typedef __attribute__((ext_vector_type(4))) unsigned int u32x4;

#define NB 64
#define SQ 198
#define SKV 206
#define DM 768
#define NH 12
#define NROWS (NB * SKV)   // 13184
#define NCOL 2304          // Q | K | V columns

static __device__ __forceinline__ unsigned short f2b(float f) {
  union { float f; unsigned u; } v; v.f = f;
  unsigned r = v.u + 0x7FFFu + ((v.u >> 16) & 1u);
  return (unsigned short)(r >> 16);
}

// ---------- build bf16 Xkv[13184][768]: rows = hidden(198) + broadcast memory(8) per batch ----------
__global__ __launch_bounds__(256) void k_conv_x(const float* __restrict__ hid,
                                                const float* __restrict__ mem,
                                                unsigned short* __restrict__ xkv) {
  int idx = (blockIdx.x * 256 + threadIdx.x) * 8;
  int r = idx / DM;
  int c = idx - r * DM;
  int b = r / SKV, s = r - b * SKV;
  const float* src = (s < SQ) ? (hid + (b * SQ + s) * DM + c)
                              : (mem + (s - SQ) * DM + c);
  float4 v0 = ((const float4*)src)[0];
  float4 v1 = ((const float4*)src)[1];
  unsigned w0 = f2b(v0.x) | ((unsigned)f2b(v0.y) << 16);
  unsigned w1 = f2b(v0.z) | ((unsigned)f2b(v0.w) << 16);
  unsigned w2 = f2b(v1.x) | ((unsigned)f2b(v1.y) << 16);
  unsigned w3 = f2b(v1.z) | ((unsigned)f2b(v1.w) << 16);
  u32x4 o = {w0, w1, w2, w3};
  *(u32x4*)(xkv + idx) = o;
}

// ---------- transpose W -> bf16 Wt[w][n][k] ----------
__global__ __launch_bounds__(256) void k_conv_w(const float* __restrict__ Wq,
                                                const float* __restrict__ Wk,
                                                const float* __restrict__ Wv,
                                                unsigned short* __restrict__ wt) {
  __shared__ float L[64][65];
  int w = blockIdx.z;
  int n0 = blockIdx.x * 64, k0 = blockIdx.y * 64;
  const float* W = (w == 0) ? Wq : (w == 1) ? Wk : Wv;
  int tid = threadIdx.x;
#pragma unroll
  for (int i = 0; i < 16; ++i) {
    int idx = i * 256 + tid;
    int lr = idx >> 6, lc = idx & 63;
    L[lr][lc] = W[(k0 + lr) * DM + n0 + lc];
  }
  __syncthreads();
  unsigned short* dst = wt + w * DM * DM;
#pragma unroll
  for (int o = 0; o < 2; ++o) {
    int gi = o * 256 + tid;
    int rn = gi >> 3, g = gi & 7;
    unsigned wrd[4];
#pragma unroll
    for (int jj = 0; jj < 4; ++jj) {
      float f0 = L[g * 8 + jj * 2 + 0][rn];
      float f1 = L[g * 8 + jj * 2 + 1][rn];
      wrd[jj] = f2b(f0) | ((unsigned)f2b(f1) << 16);
    }
    u32x4 o4 = {wrd[0], wrd[1], wrd[2], wrd[3]};
    *(u32x4*)(dst + (n0 + rn) * DM + k0 + g * 8) = o4;
  }
}

// ---------- fused QKV GEMM (unchanged from passing round 1) ----------
__global__ __launch_bounds__(256, 2) void k_gemm(const unsigned short* __restrict__ xkv,
                                                 const unsigned short* __restrict__ wt,
                                                 const float* __restrict__ bq,
                                                 const float* __restrict__ bk,
                                                 const float* __restrict__ bv,
                                                 unsigned short* __restrict__ cout) {
  __shared__ __align__(16) unsigned char smem[34816];
  int nt = blockIdx.x, mt = blockIdx.y;
  int row0 = mt * 128, col0 = nt * 128;
  int w = nt / 6;
  int colw0 = col0 - w * 768;
  int tid = threadIdx.x, lane = tid & 63, wid = tid >> 6;
  int wr = wid >> 1, wc = wid & 1;
  const unsigned short* wbase = wt + w * DM * DM;

  f32x4 zero = {0.f, 0.f, 0.f, 0.f};
  f32x4 acc[4][4];
#pragma unroll
  for (int i = 0; i < 4; ++i)
#pragma unroll
    for (int j = 0; j < 4; ++j) acc[i][j] = zero;

  int arow[4], ag[4], aoff[4];
#pragma unroll
  for (int j = 0; j < 4; ++j) {
    int sidx = j * 256 + tid;
    int r = sidx >> 3, g = sidx & 7;
    arow[j] = r;
    ag[j] = g;
    aoff[j] = (r * 128 + g * 16) ^ ((r & 7) << 4);
  }

  for (int ks = 0; ks < 12; ++ks) {
    int k0 = ks * 64;
    bf16x8 av[4], bvv[4];
#pragma unroll
    for (int j = 0; j < 4; ++j) {
      av[j]  = *(const bf16x8*)(xkv   + (row0 + arow[j])  * DM + k0 + ag[j] * 8);
      bvv[j] = *(const bf16x8*)(wbase + (colw0 + arow[j]) * DM + k0 + ag[j] * 8);
    }
    __syncthreads();
#pragma unroll
    for (int j = 0; j < 4; ++j) {
      *(bf16x8*)(smem + aoff[j]) = av[j];
      *(bf16x8*)(smem + 16384 + aoff[j]) = bvv[j];
    }
    __syncthreads();
#pragma unroll
    for (int kk = 0; kk < 2; ++kk) {
      bf16x8 a[4], b[4];
      int kbyte = (kk * 32 + ((lane >> 4) * 8)) * 2;
#pragma unroll
      for (int mi = 0; mi < 4; ++mi) {
        int rr = wr * 64 + mi * 16 + (lane & 15);
        a[mi] = *(const bf16x8*)(smem + rr * 128 + (kbyte ^ ((rr & 7) << 4)));
      }
#pragma unroll
      for (int ni = 0; ni < 4; ++ni) {
        int rr = wc * 64 + ni * 16 + (lane & 15);
        b[ni] = *(const bf16x8*)(smem + 16384 + rr * 128 + (kbyte ^ ((rr & 7) << 4)));
      }
#pragma unroll
      for (int mi = 0; mi < 4; ++mi)
#pragma unroll
        for (int ni = 0; ni < 4; ++ni)
          acc[mi][ni] = __builtin_amdgcn_mfma_f32_16x16x32_bf16(a[mi], b[ni], acc[mi][ni], 0, 0, 0);
    }
  }

  const float* bias = (w == 0) ? bq : (w == 1) ? bk : bv;
  float bb[4];
#pragma unroll
  for (int ni = 0; ni < 4; ++ni) bb[ni] = bias[colw0 + wc * 64 + ni * 16 + (lane & 15)];

  __syncthreads();
#pragma unroll
  for (int mi = 0; mi < 4; ++mi)
#pragma unroll
    for (int ni = 0; ni < 4; ++ni)
#pragma unroll
      for (int r = 0; r < 4; ++r) {
        int row = wr * 64 + mi * 16 + (lane >> 4) * 4 + r;
        int col = wc * 64 + ni * 16 + (lane & 15);
        *(unsigned short*)(smem + row * 272 + col * 2) = f2b(acc[mi][ni][r] + bb[ni]);
      }
  __syncthreads();
#pragma unroll
  for (int it = 0; it < 8; ++it) {
    int gi = it * 256 + tid;
    int row = gi >> 4, g = gi & 15;
    u32x4 v = *(const u32x4*)(smem + row * 272 + g * 16);
    *(u32x4*)(cout + (row0 + row) * NCOL + col0 + g * 8) = v;
  }
}

// ---------- attention v3: swapped QK^T, in-register P, 52KB LDS -> 3 blocks/CU ----------
// Vt layout: byte(row,col) = row*416 + (col*2 ^ (((row>>3)&1)<<4))
// XOR of bit 4 swaps adjacent 16B blocks wholesale: stays inside the row's 416B,
// keeps 16B alignment for ds_read_b128, and zero-init of cols 206/207 still lands
// on cols 206/207 (low 4 bits untouched).
static __device__ __forceinline__ int vt_off(int row, int col) {
  return row * 416 + ((col * 2) ^ (((row >> 3) & 1) << 4));
}

__global__ __launch_bounds__(256, 3) void k_attn(const unsigned short* __restrict__ cqkv,
                                                 float* __restrict__ out) {
  __shared__ __align__(16) unsigned short Ksh[208 * 64];   // swizzled [key][dh]  26624B
  __shared__ __align__(16) unsigned char  VtB[64 * 416];   // swizzled [dh][key]  26624B
  int bh = blockIdx.x;
  int b = bh / NH, h = bh - b * NH;
  int tid = threadIdx.x, lane = tid & 63, wid = tid >> 6;
  int g = lane >> 4, l = lane & 15;
  const unsigned short* Cb = cqkv + (b * SKV) * NCOL + h * 64;

  // zero Vt pad cols 206,207 (avoid NaN from poison * 0)
  if (tid < 64) *(unsigned*)(VtB + vt_off(tid, 206)) = 0u;
  // stage K swizzled (rows 206,207 duplicate row 205; masked later)
  for (int i = tid; i < 208 * 8; i += 256) {
    int row = i >> 3, gg = i & 7;
    int srow = (row < SKV) ? row : (SKV - 1);
    u32x4 v = *(const u32x4*)(Cb + srow * NCOL + 768 + gg * 8);
    *(u32x4*)((unsigned char*)Ksh + ((row * 128 + gg * 16) ^ ((row & 7) << 4))) = v;
  }
  // stage V transposed into swizzled layout
  for (int i = tid; i < 206 * 8; i += 256) {
    int key = i >> 3, gg = i & 7;
    u32x4 v = *(const u32x4*)(Cb + key * NCOL + 1536 + gg * 8);
    union { u32x4 v4; unsigned short e[8]; } u; u.v4 = v;
#pragma unroll
    for (int j = 0; j < 8; ++j)
      *(unsigned short*)(VtB + vt_off(gg * 8 + j, key)) = u.e[j];
  }
  __syncthreads();

  const float scale = 0.125f;
  f32x4 zero4 = {0.f, 0.f, 0.f, 0.f};
  int srcA = ((g & 1) << 5) + l;   // source lane for A-frag words 0,1
  int srcB = srcA + 16;            // for words 2,3
  bool hiHalf = (g >= 2);

  for (int qt = wid; qt < 13; qt += 4) {
    int qr = qt * 16 + l;                       // this lane's q column
    int qld = qr > 197 ? 197 : qr;
    const unsigned short* qp = Cb + qld * NCOL + g * 8;
    bf16x8 qa0 = *(const bf16x8*)qp;            // Q[q][g*8..], k-chunk 0
    bf16x8 qa1 = *(const bf16x8*)(qp + 32);     // k-chunk 1

    // swapped QK^T: sc[nt][r] = S[key = nt*16 + 4g + r][q = qt*16 + l]
    f32x4 sc[13];
#pragma unroll
    for (int nt = 0; nt < 13; ++nt) sc[nt] = zero4;
#pragma unroll
    for (int nt = 0; nt < 13; ++nt) {
      int key = nt * 16 + l;
      int rb = key * 128, sw = (key & 7) << 4, kb = g * 16;
      bf16x8 kb0 = *(const bf16x8*)((const unsigned char*)Ksh + rb + (kb ^ sw));
      bf16x8 kb1 = *(const bf16x8*)((const unsigned char*)Ksh + rb + ((kb + 64) ^ sw));
      sc[nt] = __builtin_amdgcn_mfma_f32_16x16x32_bf16(kb0, qa0, sc[nt], 0, 0, 0);
      sc[nt] = __builtin_amdgcn_mfma_f32_16x16x32_bf16(kb1, qa1, sc[nt], 0, 0, 0);
    }

    // mask + scale + max (per-lane over its 52 keys, then across the 4 key-groups)
    float mx = -1e30f;
#pragma unroll
    for (int nt = 0; nt < 13; ++nt)
#pragma unroll
      for (int r = 0; r < 4; ++r) {
        int key = nt * 16 + g * 4 + r;
        float s = sc[nt][r] * scale;
        bool ok = (key < 197 || qr == 197) && (key < SKV);
        s = ok ? s : -1e30f;
        sc[nt][r] = s;
        mx = fmaxf(mx, s);
      }
    mx = fmaxf(mx, __shfl_xor(mx, 16));
    mx = fmaxf(mx, __shfl_xor(mx, 32));
    float sum = 0.f;
#pragma unroll
    for (int nt = 0; nt < 13; ++nt)
#pragma unroll
      for (int r = 0; r < 4; ++r) {
        float p = __expf(sc[nt][r] - mx);
        sc[nt][r] = p;
        sum += p;
      }
    sum += __shfl_xor(sum, 16);
    sum += __shfl_xor(sum, 32);
    float inv = 1.0f / sum;

    // pack unnormalized P to bf16 pairs
    unsigned pk0[13], pk1[13];
#pragma unroll
    for (int nt = 0; nt < 13; ++nt) {
      asm("v_cvt_pk_bf16_f32 %0, %1, %2" : "=v"(pk0[nt]) : "v"(sc[nt][0]), "v"(sc[nt][1]));
      asm("v_cvt_pk_bf16_f32 %0, %1, %2" : "=v"(pk1[nt]) : "v"(sc[nt][2]), "v"(sc[nt][3]));
    }

    // PV: build A-frag per 32-key chunk via shfl exchange, B from swizzled Vt
    f32x4 ctx[4];
#pragma unroll
    for (int dt = 0; dt < 4; ++dt) ctx[dt] = zero4;
#pragma unroll
    for (int c = 0; c < 7; ++c) {
      union { unsigned w[4]; bf16x8 v; } pa;
      if (c < 6) {
        int n0 = 2 * c, n1 = 2 * c + 1;
        unsigned a0 = (unsigned)__shfl((int)pk0[n0], srcA), b0 = (unsigned)__shfl((int)pk0[n1], srcA);
        unsigned a1 = (unsigned)__shfl((int)pk1[n0], srcA), b1 = (unsigned)__shfl((int)pk1[n1], srcA);
        unsigned a2 = (unsigned)__shfl((int)pk0[n0], srcB), b2 = (unsigned)__shfl((int)pk0[n1], srcB);
        unsigned a3 = (unsigned)__shfl((int)pk1[n0], srcB), b3 = (unsigned)__shfl((int)pk1[n1], srcB);
        pa.w[0] = hiHalf ? b0 : a0;
        pa.w[1] = hiHalf ? b1 : a1;
        pa.w[2] = hiHalf ? b2 : a2;
        pa.w[3] = hiHalf ? b3 : a3;
      } else {           // keys 192..223: hi half (keys >= 208) all-masked -> zeros
        unsigned a0 = (unsigned)__shfl((int)pk0[12], srcA);
        unsigned a1 = (unsigned)__shfl((int)pk1[12], srcA);
        unsigned a2 = (unsigned)__shfl((int)pk0[12], srcB);
        unsigned a3 = (unsigned)__shfl((int)pk1[12], srcB);
        pa.w[0] = hiHalf ? 0u : a0;
        pa.w[1] = hiHalf ? 0u : a1;
        pa.w[2] = hiHalf ? 0u : a2;
        pa.w[3] = hiHalf ? 0u : a3;
      }
      int colb = c * 32 + g * 8;
      if (c == 6 && hiHalf) colb = 0;   // pa==0 there, any valid addr
#pragma unroll
      for (int dt = 0; dt < 4; ++dt) {
        bf16x8 vb = *(const bf16x8*)(VtB + vt_off(dt * 16 + l, colb));
        ctx[dt] = __builtin_amdgcn_mfma_f32_16x16x32_bf16(pa.v, vb, ctx[dt], 0, 0, 0);
      }
    }

    // deferred normalization: output row q = qt*16 + 4g + r needs inv from lane (4g+r)
    float invr[4];
#pragma unroll
    for (int r = 0; r < 4; ++r) invr[r] = __shfl(inv, g * 4 + r);
#pragma unroll
    for (int dt = 0; dt < 4; ++dt)
#pragma unroll
      for (int r = 0; r < 4; ++r) {
        int qo = qt * 16 + g * 4 + r;
        if (qo < SQ)
          out[(b * SQ + qo) * DM + h * 64 + dt * 16 + l] = ctx[dt][r] * invr[r];
      }
  }
}

extern "C" void kernel_launch(void* const* d_in, const int* in_sizes, int n_in,
                              void* d_out, int out_size, void* d_ws, size_t ws_size,
                              hipStream_t stream) {
  const float* hid = (const float*)d_in[0];
  const float* mem = (const float*)d_in[1];
  const float* Wq  = (const float*)d_in[2];
  const float* bq  = (const float*)d_in[3];
  const float* Wk  = (const float*)d_in[4];
  const float* bk  = (const float*)d_in[5];
  const float* Wv  = (const float*)d_in[6];
  const float* bv  = (const float*)d_in[7];
  float* out = (float*)d_out;

  unsigned short* xkv  = (unsigned short*)d_ws;
  unsigned short* wt   = xkv + NROWS * DM;
  unsigned short* cbuf = wt + 3 * DM * DM;

  k_conv_x<<<dim3(NROWS * DM / 8 / 256), 256, 0, stream>>>(hid, mem, xkv);
  k_conv_w<<<dim3(12, 12, 3), 256, 0, stream>>>(Wq, Wk, Wv, wt);
  k_gemm<<<dim3(18, 103), 256, 0, stream>>>(xkv, wt, bq, bk, bv, cbuf);
  k_attn<<<dim3(NB * NH), 256, 0, stream>>>(cbuf, out);
}

// Round 4
// 105.673 us; speedup vs baseline: 1.3401x; 1.0414x over previous
//
#include <hip/hip_runtime.h>

typedef __attribute__((ext_vector_type(8))) short bf16x8;
typedef __attribute__((ext_vector_type(4))) float f32x4;
typedef __attribute__((ext_vector_type(4))) unsigned int u32x4;

#define NB 64
#define SQ 198
#define SKV 206
#define DM 768
#define NH 12
#define NROWS (NB * SKV)   // 13184
#define NCOL 2304          // Q | K | V columns

static __device__ __forceinline__ unsigned short f2b(float f) {
  union { float f; unsigned u; } v; v.f = f;
  unsigned r = v.u + 0x7FFFu + ((v.u >> 16) & 1u);
  return (unsigned short)(r >> 16);
}

typedef const __attribute__((address_space(1))) unsigned int g_u32;
typedef __attribute__((address_space(3))) unsigned int l_u32;
static __device__ __forceinline__ void gload_lds16(const void* g, void* l) {
  __builtin_amdgcn_global_load_lds((g_u32*)g, (l_u32*)l, 16, 0, 0);
}

// ---------- build bf16 Xkv[13184][768]: rows = hidden(198) + broadcast memory(8) per batch ----------
__global__ __launch_bounds__(256) void k_conv_x(const float* __restrict__ hid,
                                                const float* __restrict__ mem,
                                                unsigned short* __restrict__ xkv) {
  int idx = (blockIdx.x * 256 + threadIdx.x) * 8;
  int r = idx / DM;
  int c = idx - r * DM;
  int b = r / SKV, s = r - b * SKV;
  const float* src = (s < SQ) ? (hid + (b * SQ + s) * DM + c)
                              : (mem + (s - SQ) * DM + c);
  float4 v0 = ((const float4*)src)[0];
  float4 v1 = ((const float4*)src)[1];
  unsigned w0 = f2b(v0.x) | ((unsigned)f2b(v0.y) << 16);
  unsigned w1 = f2b(v0.z) | ((unsigned)f2b(v0.w) << 16);
  unsigned w2 = f2b(v1.x) | ((unsigned)f2b(v1.y) << 16);
  unsigned w3 = f2b(v1.z) | ((unsigned)f2b(v1.w) << 16);
  u32x4 o = {w0, w1, w2, w3};
  *(u32x4*)(xkv + idx) = o;
}

// ---------- transpose W -> bf16 Wt[w][n][k] ----------
__global__ __launch_bounds__(256) void k_conv_w(const float* __restrict__ Wq,
                                                const float* __restrict__ Wk,
                                                const float* __restrict__ Wv,
                                                unsigned short* __restrict__ wt) {
  __shared__ float L[64][65];
  int w = blockIdx.z;
  int n0 = blockIdx.x * 64, k0 = blockIdx.y * 64;
  const float* W = (w == 0) ? Wq : (w == 1) ? Wk : Wv;
  int tid = threadIdx.x;
#pragma unroll
  for (int i = 0; i < 16; ++i) {
    int idx = i * 256 + tid;
    int lr = idx >> 6, lc = idx & 63;
    L[lr][lc] = W[(k0 + lr) * DM + n0 + lc];
  }
  __syncthreads();
  unsigned short* dst = wt + w * DM * DM;
#pragma unroll
  for (int o = 0; o < 2; ++o) {
    int gi = o * 256 + tid;
    int rn = gi >> 3, g = gi & 7;
    unsigned wrd[4];
#pragma unroll
    for (int jj = 0; jj < 4; ++jj) {
      float f0 = L[g * 8 + jj * 2 + 0][rn];
      float f1 = L[g * 8 + jj * 2 + 1][rn];
      wrd[jj] = f2b(f0) | ((unsigned)f2b(f1) << 16);
    }
    u32x4 o4 = {wrd[0], wrd[1], wrd[2], wrd[3]};
    *(u32x4*)(dst + (n0 + rn) * DM + k0 + g * 8) = o4;
  }
}

// ---------- fused QKV GEMM: global_load_lds staging (pre-swizzled source, linear dest) ----------
__global__ __launch_bounds__(256, 2) void k_gemm(const unsigned short* __restrict__ xkv,
                                                 const unsigned short* __restrict__ wt,
                                                 const float* __restrict__ bq,
                                                 const float* __restrict__ bk,
                                                 const float* __restrict__ bv,
                                                 unsigned short* __restrict__ cout) {
  __shared__ __align__(16) unsigned char smem[34816];
  int nt = blockIdx.x, mt = blockIdx.y;
  int row0 = mt * 128, col0 = nt * 128;
  int w = nt / 6;
  int colw0 = col0 - w * 768;
  int tid = threadIdx.x, lane = tid & 63, wid = tid >> 6;
  int wr = wid >> 1, wc = wid & 1;
  const unsigned short* wbase = wt + w * DM * DM;

  f32x4 zero = {0.f, 0.f, 0.f, 0.f};
  f32x4 acc[4][4];
#pragma unroll
  for (int i = 0; i < 4; ++i)
#pragma unroll
    for (int j = 0; j < 4; ++j) acc[i][j] = zero;

  // staging: LDS granule s=(wid*4+j)*64+lane holds source granule (r, g^(r&7)),
  // r=s>>3, g=s&7 — inverse of the XOR swizzle the read side applies.
  const unsigned short* aSrc[4];
  const unsigned short* bSrc[4];
#pragma unroll
  for (int j = 0; j < 4; ++j) {
    int s = (wid * 4 + j) * 64 + lane;
    int r = s >> 3, g = s & 7;
    int gsrc = g ^ (r & 7);
    aSrc[j] = xkv   + (row0 + r)  * DM + gsrc * 8;
    bSrc[j] = wbase + (colw0 + r) * DM + gsrc * 8;
  }

  for (int ks = 0; ks < 12; ++ks) {
    int k0 = ks * 64;
    if (ks) __syncthreads();          // previous compute done reading LDS
#pragma unroll
    for (int j = 0; j < 4; ++j) {
      gload_lds16(aSrc[j] + k0, smem + (wid * 4 + j) * 1024);
      gload_lds16(bSrc[j] + k0, smem + 16384 + (wid * 4 + j) * 1024);
    }
    __syncthreads();                  // vmcnt drain + tile staged
#pragma unroll
    for (int kk = 0; kk < 2; ++kk) {
      bf16x8 a[4], b[4];
      int kbyte = (kk * 32 + ((lane >> 4) * 8)) * 2;
#pragma unroll
      for (int mi = 0; mi < 4; ++mi) {
        int rr = wr * 64 + mi * 16 + (lane & 15);
        a[mi] = *(const bf16x8*)(smem + ((rr * 128 + kbyte) ^ ((rr & 7) << 4)));
      }
#pragma unroll
      for (int ni = 0; ni < 4; ++ni) {
        int rr = wc * 64 + ni * 16 + (lane & 15);
        b[ni] = *(const bf16x8*)(smem + 16384 + ((rr * 128 + kbyte) ^ ((rr & 7) << 4)));
      }
#pragma unroll
      for (int mi = 0; mi < 4; ++mi)
#pragma unroll
        for (int ni = 0; ni < 4; ++ni)
          acc[mi][ni] = __builtin_amdgcn_mfma_f32_16x16x32_bf16(a[mi], b[ni], acc[mi][ni], 0, 0, 0);
    }
  }

  const float* bias = (w == 0) ? bq : (w == 1) ? bk : bv;
  float bb[4];
#pragma unroll
  for (int ni = 0; ni < 4; ++ni) bb[ni] = bias[colw0 + wc * 64 + ni * 16 + (lane & 15)];

  __syncthreads();
#pragma unroll
  for (int mi = 0; mi < 4; ++mi)
#pragma unroll
    for (int ni = 0; ni < 4; ++ni)
#pragma unroll
      for (int r = 0; r < 4; ++r) {
        int row = wr * 64 + mi * 16 + (lane >> 4) * 4 + r;
        int col = wc * 64 + ni * 16 + (lane & 15);
        *(unsigned short*)(smem + row * 272 + col * 2) = f2b(acc[mi][ni][r] + bb[ni]);
      }
  __syncthreads();
#pragma unroll
  for (int it = 0; it < 8; ++it) {
    int gi = it * 256 + tid;
    int row = gi >> 4, g = gi & 15;
    u32x4 v = *(const u32x4*)(smem + row * 272 + g * 16);
    *(u32x4*)(cout + (row0 + row) * NCOL + col0 + g * 8) = v;
  }
}

// ---------- attention v3 (unchanged): swapped QK^T, in-register P, 52KB LDS ----------
static __device__ __forceinline__ int vt_off(int row, int col) {
  return row * 416 + ((col * 2) ^ (((row >> 3) & 1) << 4));
}

__global__ __launch_bounds__(256, 3) void k_attn(const unsigned short* __restrict__ cqkv,
                                                 float* __restrict__ out) {
  __shared__ __align__(16) unsigned short Ksh[208 * 64];   // swizzled [key][dh]  26624B
  __shared__ __align__(16) unsigned char  VtB[64 * 416];   // swizzled [dh][key]  26624B
  int bh = blockIdx.x;
  int b = bh / NH, h = bh - b * NH;
  int tid = threadIdx.x, lane = tid & 63, wid = tid >> 6;
  int g = lane >> 4, l = lane & 15;
  const unsigned short* Cb = cqkv + (b * SKV) * NCOL + h * 64;

  if (tid < 64) *(unsigned*)(VtB + vt_off(tid, 206)) = 0u;
  for (int i = tid; i < 208 * 8; i += 256) {
    int row = i >> 3, gg = i & 7;
    int srow = (row < SKV) ? row : (SKV - 1);
    u32x4 v = *(const u32x4*)(Cb + srow * NCOL + 768 + gg * 8);
    *(u32x4*)((unsigned char*)Ksh + ((row * 128 + gg * 16) ^ ((row & 7) << 4))) = v;
  }
  for (int i = tid; i < 206 * 8; i += 256) {
    int key = i >> 3, gg = i & 7;
    u32x4 v = *(const u32x4*)(Cb + key * NCOL + 1536 + gg * 8);
    union { u32x4 v4; unsigned short e[8]; } u; u.v4 = v;
#pragma unroll
    for (int j = 0; j < 8; ++j)
      *(unsigned short*)(VtB + vt_off(gg * 8 + j, key)) = u.e[j];
  }
  __syncthreads();

  const float scale = 0.125f;
  f32x4 zero4 = {0.f, 0.f, 0.f, 0.f};
  int srcA = ((g & 1) << 5) + l;
  int srcB = srcA + 16;
  bool hiHalf = (g >= 2);

  for (int qt = wid; qt < 13; qt += 4) {
    int qr = qt * 16 + l;
    int qld = qr > 197 ? 197 : qr;
    const unsigned short* qp = Cb + qld * NCOL + g * 8;
    bf16x8 qa0 = *(const bf16x8*)qp;
    bf16x8 qa1 = *(const bf16x8*)(qp + 32);

    f32x4 sc[13];
#pragma unroll
    for (int nt = 0; nt < 13; ++nt) sc[nt] = zero4;
#pragma unroll
    for (int nt = 0; nt < 13; ++nt) {
      int key = nt * 16 + l;
      int rb = key * 128, sw = (key & 7) << 4, kb = g * 16;
      bf16x8 kb0 = *(const bf16x8*)((const unsigned char*)Ksh + rb + (kb ^ sw));
      bf16x8 kb1 = *(const bf16x8*)((const unsigned char*)Ksh + rb + ((kb + 64) ^ sw));
      sc[nt] = __builtin_amdgcn_mfma_f32_16x16x32_bf16(kb0, qa0, sc[nt], 0, 0, 0);
      sc[nt] = __builtin_amdgcn_mfma_f32_16x16x32_bf16(kb1, qa1, sc[nt], 0, 0, 0);
    }

    float mx = -1e30f;
#pragma unroll
    for (int nt = 0; nt < 13; ++nt)
#pragma unroll
      for (int r = 0; r < 4; ++r) {
        int key = nt * 16 + g * 4 + r;
        float s = sc[nt][r] * scale;
        bool ok = (key < 197 || qr == 197) && (key < SKV);
        s = ok ? s : -1e30f;
        sc[nt][r] = s;
        mx = fmaxf(mx, s);
      }
    mx = fmaxf(mx, __shfl_xor(mx, 16));
    mx = fmaxf(mx, __shfl_xor(mx, 32));
    float sum = 0.f;
#pragma unroll
    for (int nt = 0; nt < 13; ++nt)
#pragma unroll
      for (int r = 0; r < 4; ++r) {
        float p = __expf(sc[nt][r] - mx);
        sc[nt][r] = p;
        sum += p;
      }
    sum += __shfl_xor(sum, 16);
    sum += __shfl_xor(sum, 32);
    float inv = 1.0f / sum;

    unsigned pk0[13], pk1[13];
#pragma unroll
    for (int nt = 0; nt < 13; ++nt) {
      asm("v_cvt_pk_bf16_f32 %0, %1, %2" : "=v"(pk0[nt]) : "v"(sc[nt][0]), "v"(sc[nt][1]));
      asm("v_cvt_pk_bf16_f32 %0, %1, %2" : "=v"(pk1[nt]) : "v"(sc[nt][2]), "v"(sc[nt][3]));
    }

    f32x4 ctx[4];
#pragma unroll
    for (int dt = 0; dt < 4; ++dt) ctx[dt] = zero4;
#pragma unroll
    for (int c = 0; c < 7; ++c) {
      union { unsigned w[4]; bf16x8 v; } pa;
      if (c < 6) {
        int n0 = 2 * c, n1 = 2 * c + 1;
        unsigned a0 = (unsigned)__shfl((int)pk0[n0], srcA), b0 = (unsigned)__shfl((int)pk0[n1], srcA);
        unsigned a1 = (unsigned)__shfl((int)pk1[n0], srcA), b1 = (unsigned)__shfl((int)pk1[n1], srcA);
        unsigned a2 = (unsigned)__shfl((int)pk0[n0], srcB), b2 = (unsigned)__shfl((int)pk0[n1], srcB);
        unsigned a3 = (unsigned)__shfl((int)pk1[n0], srcB), b3 = (unsigned)__shfl((int)pk1[n1], srcB);
        pa.w[0] = hiHalf ? b0 : a0;
        pa.w[1] = hiHalf ? b1 : a1;
        pa.w[2] = hiHalf ? b2 : a2;
        pa.w[3] = hiHalf ? b3 : a3;
      } else {
        unsigned a0 = (unsigned)__shfl((int)pk0[12], srcA);
        unsigned a1 = (unsigned)__shfl((int)pk1[12], srcA);
        unsigned a2 = (unsigned)__shfl((int)pk0[12], srcB);
        unsigned a3 = (unsigned)__shfl((int)pk1[12], srcB);
        pa.w[0] = hiHalf ? 0u : a0;
        pa.w[1] = hiHalf ? 0u : a1;
        pa.w[2] = hiHalf ? 0u : a2;
        pa.w[3] = hiHalf ? 0u : a3;
      }
      int colb = c * 32 + g * 8;
      if (c == 6 && hiHalf) colb = 0;
#pragma unroll
      for (int dt = 0; dt < 4; ++dt) {
        bf16x8 vb = *(const bf16x8*)(VtB + vt_off(dt * 16 + l, colb));
        ctx[dt] = __builtin_amdgcn_mfma_f32_16x16x32_bf16(pa.v, vb, ctx[dt], 0, 0, 0);
      }
    }

    float invr[4];
#pragma unroll
    for (int r = 0; r < 4; ++r) invr[r] = __shfl(inv, g * 4 + r);
#pragma unroll
    for (int dt = 0; dt < 4; ++dt)
#pragma unroll
      for (int r = 0; r < 4; ++r) {
        int qo = qt * 16 + g * 4 + r;
        if (qo < SQ)
          out[(b * SQ + qo) * DM + h * 64 + dt * 16 + l] = ctx[dt][r] * invr[r];
      }
  }
}

extern "C" void kernel_launch(void* const* d_in, const int* in_sizes, int n_in,
                              void* d_out, int out_size, void* d_ws, size_t ws_size,
                              hipStream_t stream) {
  const float* hid = (const float*)d_in[0];
  const float* mem = (const float*)d_in[1];
  const float* Wq  = (const float*)d_in[2];
  const float* bq  = (const float*)d_in[3];
  const float* Wk  = (const float*)d_in[4];
  const float* bk  = (const float*)d_in[5];
  const float* Wv  = (const float*)d_in[6];
  const float* bv  = (const float*)d_in[7];
  float* out = (float*)d_out;

  unsigned short* xkv  = (unsigned short*)d_ws;
  unsigned short* wt   = xkv + NROWS * DM;
  unsigned short* cbuf = wt + 3 * DM * DM;

  k_conv_x<<<dim3(NROWS * DM / 8 / 256), 256, 0, stream>>>(hid, mem, xkv);
  k_conv_w<<<dim3(12, 12, 3), 256, 0, stream>>>(Wq, Wk, Wv, wt);
  k_gemm<<<dim3(18, 103), 256, 0, stream>>>(xkv, wt, bq, bk, bv, cbuf);
  k_attn<<<dim3(NB * NH), 256, 0, stream>>>(cbuf, out);
}

// Round 5
// 105.049 us; speedup vs baseline: 1.3481x; 1.0059x over previous
//
#include <hip/hip_runtime.h>

typedef __attribute__((ext_vector_type(8))) short bf16x8;
typedef __attribute__((ext_vector_type(4))) float f32x4;
typedef __attribute__((ext_vector_type(4))) unsigned int u32x4;

#define NB 64
#define SQ 198
#define SKV 206
#define DM 768
#define NH 12
#define NROWS (NB * SKV)   // 13184
#define NCOL 2304          // Q | K | V columns

static __device__ __forceinline__ unsigned short f2b(float f) {
  union { float f; unsigned u; } v; v.f = f;
  unsigned r = v.u + 0x7FFFu + ((v.u >> 16) & 1u);
  return (unsigned short)(r >> 16);
}

typedef const __attribute__((address_space(1))) unsigned int g_u32;
typedef __attribute__((address_space(3))) unsigned int l_u32;
static __device__ __forceinline__ void gload_lds16(const void* g, void* l) {
  __builtin_amdgcn_global_load_lds((g_u32*)g, (l_u32*)l, 16, 0, 0);
}

// ---------- build bf16 Xkv[13184][768] ----------
__global__ __launch_bounds__(256) void k_conv_x(const float* __restrict__ hid,
                                                const float* __restrict__ mem,
                                                unsigned short* __restrict__ xkv) {
  int idx = (blockIdx.x * 256 + threadIdx.x) * 8;
  int r = idx / DM;
  int c = idx - r * DM;
  int b = r / SKV, s = r - b * SKV;
  const float* src = (s < SQ) ? (hid + (b * SQ + s) * DM + c)
                              : (mem + (s - SQ) * DM + c);
  float4 v0 = ((const float4*)src)[0];
  float4 v1 = ((const float4*)src)[1];
  unsigned w0 = f2b(v0.x) | ((unsigned)f2b(v0.y) << 16);
  unsigned w1 = f2b(v0.z) | ((unsigned)f2b(v0.w) << 16);
  unsigned w2 = f2b(v1.x) | ((unsigned)f2b(v1.y) << 16);
  unsigned w3 = f2b(v1.z) | ((unsigned)f2b(v1.w) << 16);
  u32x4 o = {w0, w1, w2, w3};
  *(u32x4*)(xkv + idx) = o;
}

// ---------- transpose W -> bf16 Wt[w][n][k] ----------
__global__ __launch_bounds__(256) void k_conv_w(const float* __restrict__ Wq,
                                                const float* __restrict__ Wk,
                                                const float* __restrict__ Wv,
                                                unsigned short* __restrict__ wt) {
  __shared__ float L[64][65];
  int w = blockIdx.z;
  int n0 = blockIdx.x * 64, k0 = blockIdx.y * 64;
  const float* W = (w == 0) ? Wq : (w == 1) ? Wk : Wv;
  int tid = threadIdx.x;
#pragma unroll
  for (int i = 0; i < 16; ++i) {
    int idx = i * 256 + tid;
    int lr = idx >> 6, lc = idx & 63;
    L[lr][lc] = W[(k0 + lr) * DM + n0 + lc];
  }
  __syncthreads();
  unsigned short* dst = wt + w * DM * DM;
#pragma unroll
  for (int o = 0; o < 2; ++o) {
    int gi = o * 256 + tid;
    int rn = gi >> 3, g = gi & 7;
    unsigned wrd[4];
#pragma unroll
    for (int jj = 0; jj < 4; ++jj) {
      float f0 = L[g * 8 + jj * 2 + 0][rn];
      float f1 = L[g * 8 + jj * 2 + 1][rn];
      wrd[jj] = f2b(f0) | ((unsigned)f2b(f1) << 16);
    }
    u32x4 o4 = {wrd[0], wrd[1], wrd[2], wrd[3]};
    *(u32x4*)(dst + (n0 + rn) * DM + k0 + g * 8) = o4;
  }
}

// ---------- fused QKV GEMM v2: 256x256 tile, BK=32, 4-buf pipeline, counted vmcnt ----------
// LDS: A bufs [0,64K) 4x16KB, B bufs [64K,128K) 4x16KB. Rows of 64B (32 bf16),
// granule swizzle: physical granule = logical ^ (row&3). Staged with linear-dest
// global_load_lds from pre-swizzled source (both-sides involution).
__global__ __launch_bounds__(512, 2) void k_gemm(const unsigned short* __restrict__ xkv,
                                                 const unsigned short* __restrict__ wt,
                                                 const float* __restrict__ bq,
                                                 const float* __restrict__ bk,
                                                 const float* __restrict__ bv,
                                                 unsigned short* __restrict__ cout) {
  __shared__ __align__(16) unsigned char smem[131072];
  // bijective XCD swizzle (nwg=468: q=58, r=4): 9 N-tiles sharing an A-panel -> same XCD
  int o = blockIdx.x, xcd = o & 7, rest = o >> 3;
  int sid = (xcd < 4 ? xcd * 59 : 236 + (xcd - 4) * 58) + rest;
  int mtile = sid / 9, ntile = sid - mtile * 9;
  int row0 = mtile * 256, col0 = ntile * 256;
  int w = ntile / 3;
  int colw0 = (ntile - w * 3) * 256;
  int tid = threadIdx.x, lane = tid & 63, wid = tid >> 6;
  int wm = wid >> 2, wn = wid & 3;      // 2M x 4N waves
  int l = lane & 15, gq = lane >> 4;
  const unsigned short* wbase = wt + w * DM * DM;

  // staging source (per-thread): slot tid -> row sr, phys granule pg, src granule sg
  int sr = tid >> 2, pg = tid & 3, sg = pg ^ (sr & 3);
  int arow0 = row0 + sr;        if (arow0 > NROWS - 1) arow0 = NROWS - 1;
  int arow1 = row0 + 128 + sr;  if (arow1 > NROWS - 1) arow1 = NROWS - 1;
  const unsigned short* aP0 = xkv + arow0 * DM + sg * 8;
  const unsigned short* aP1 = xkv + arow1 * DM + sg * 8;
  const unsigned short* bP0 = wbase + (colw0 + sr) * DM + sg * 8;
  const unsigned short* bP1 = wbase + (colw0 + 128 + sr) * DM + sg * 8;
  int ldsW = wid * 1024;                // wave-uniform LDS base (lane*16 added by HW)

  f32x4 zero = {0.f, 0.f, 0.f, 0.f};
  f32x4 acc[8][4];
#pragma unroll
  for (int i = 0; i < 8; ++i)
#pragma unroll
    for (int j = 0; j < 4; ++j) acc[i][j] = zero;

  // prologue: issue K-tiles 0,1,2 (12 loads/thread in flight)
#pragma unroll
  for (int p = 0; p < 3; ++p) {
    gload_lds16(aP0 + p * 32, smem + p * 16384 + ldsW);
    gload_lds16(aP1 + p * 32, smem + p * 16384 + 8192 + ldsW);
    gload_lds16(bP0 + p * 32, smem + 65536 + p * 16384 + ldsW);
    gload_lds16(bP1 + p * 32, smem + 65536 + p * 16384 + 8192 + ldsW);
  }

  // read-address components: row&3 == l&3 for all fragments
  int swx = (gq * 16) ^ ((l & 3) << 4);
  int aRd = (wm * 128 + l) * 64 + swx;            // + mi*1024 + bufOff
  int bRd = 65536 + (wn * 64 + l) * 64 + swx;     // + ni*1024 + bufOff

  auto doTile = [&](int t) {
    int bo = (t & 3) * 16384;
    bf16x8 a[8], b[4];
#pragma unroll
    for (int mi = 0; mi < 8; ++mi) a[mi] = *(const bf16x8*)(smem + bo + aRd + mi * 1024);
#pragma unroll
    for (int ni = 0; ni < 4; ++ni) b[ni] = *(const bf16x8*)(smem + bo + bRd + ni * 1024);
    __builtin_amdgcn_s_setprio(1);
#pragma unroll
    for (int mi = 0; mi < 8; ++mi)
#pragma unroll
      for (int ni = 0; ni < 4; ++ni)
        acc[mi][ni] = __builtin_amdgcn_mfma_f32_16x16x32_bf16(a[mi], b[ni], acc[mi][ni], 0, 0, 0);
    __builtin_amdgcn_s_setprio(0);
  };

#pragma unroll 1
  for (int t = 0; t < 22; ++t) {
    asm volatile("s_waitcnt vmcnt(8)" ::: "memory");   // tile t resident; t+1,t+2 in flight
    __builtin_amdgcn_s_barrier();
    asm volatile("" ::: "memory");
    if (t < 21) {                                      // issue tile t+3 into buf (t-1) vacated
      int io = ((t + 3) & 3) * 16384;
      int kI = (t + 3) * 32;
      gload_lds16(aP0 + kI, smem + io + ldsW);
      gload_lds16(aP1 + kI, smem + io + 8192 + ldsW);
      gload_lds16(bP0 + kI, smem + 65536 + io + ldsW);
      gload_lds16(bP1 + kI, smem + 65536 + io + 8192 + ldsW);
    }
    doTile(t);
  }
  asm volatile("s_waitcnt vmcnt(4)" ::: "memory");
  __builtin_amdgcn_s_barrier();
  asm volatile("" ::: "memory");
  doTile(22);
  asm volatile("s_waitcnt vmcnt(0)" ::: "memory");
  __builtin_amdgcn_s_barrier();
  asm volatile("" ::: "memory");
  doTile(23);

  // epilogue: bias + bf16 C through LDS (row-major [256][512B], (row&7)<<4 XOR)
  const float* bias = (w == 0) ? bq : (w == 1) ? bk : bv;
  float bb[4];
#pragma unroll
  for (int ni = 0; ni < 4; ++ni) bb[ni] = bias[colw0 + wn * 64 + ni * 16 + l];

  __syncthreads();   // full drain; safe to overwrite A/B buffers with C
#pragma unroll
  for (int mi = 0; mi < 8; ++mi)
#pragma unroll
    for (int ni = 0; ni < 4; ++ni)
#pragma unroll
      for (int rr = 0; rr < 4; ++rr) {
        int row = wm * 128 + mi * 16 + gq * 4 + rr;
        int col = wn * 64 + ni * 16 + l;
        *(unsigned short*)(smem + row * 512 + ((col * 2) ^ ((row & 7) << 4))) =
            f2b(acc[mi][ni][rr] + bb[ni]);
      }
  __syncthreads();
#pragma unroll
  for (int it = 0; it < 16; ++it) {
    int gi = it * 512 + tid;
    int row = gi >> 5, gran = gi & 31;
    if (row0 + row < NROWS) {
      u32x4 v = *(const u32x4*)(smem + row * 512 + ((gran * 16) ^ ((row & 7) << 4)));
      *(u32x4*)(cout + (row0 + row) * NCOL + col0 + gran * 8) = v;
    }
  }
}

// ---------- attention (unchanged): swapped QK^T, in-register P, 52KB LDS ----------
static __device__ __forceinline__ int vt_off(int row, int col) {
  return row * 416 + ((col * 2) ^ (((row >> 3) & 1) << 4));
}

__global__ __launch_bounds__(256, 3) void k_attn(const unsigned short* __restrict__ cqkv,
                                                 float* __restrict__ out) {
  __shared__ __align__(16) unsigned short Ksh[208 * 64];
  __shared__ __align__(16) unsigned char  VtB[64 * 416];
  int bh = blockIdx.x;
  int b = bh / NH, h = bh - b * NH;
  int tid = threadIdx.x, lane = tid & 63, wid = tid >> 6;
  int g = lane >> 4, l = lane & 15;
  const unsigned short* Cb = cqkv + (b * SKV) * NCOL + h * 64;

  if (tid < 64) *(unsigned*)(VtB + vt_off(tid, 206)) = 0u;
  for (int i = tid; i < 208 * 8; i += 256) {
    int row = i >> 3, gg = i & 7;
    int srow = (row < SKV) ? row : (SKV - 1);
    u32x4 v = *(const u32x4*)(Cb + srow * NCOL + 768 + gg * 8);
    *(u32x4*)((unsigned char*)Ksh + ((row * 128 + gg * 16) ^ ((row & 7) << 4))) = v;
  }
  for (int i = tid; i < 206 * 8; i += 256) {
    int key = i >> 3, gg = i & 7;
    u32x4 v = *(const u32x4*)(Cb + key * NCOL + 1536 + gg * 8);
    union { u32x4 v4; unsigned short e[8]; } u; u.v4 = v;
#pragma unroll
    for (int j = 0; j < 8; ++j)
      *(unsigned short*)(VtB + vt_off(gg * 8 + j, key)) = u.e[j];
  }
  __syncthreads();

  const float scale = 0.125f;
  f32x4 zero4 = {0.f, 0.f, 0.f, 0.f};
  int srcA = ((g & 1) << 5) + l;
  int srcB = srcA + 16;
  bool hiHalf = (g >= 2);

  for (int qt = wid; qt < 13; qt += 4) {
    int qr = qt * 16 + l;
    int qld = qr > 197 ? 197 : qr;
    const unsigned short* qp = Cb + qld * NCOL + g * 8;
    bf16x8 qa0 = *(const bf16x8*)qp;
    bf16x8 qa1 = *(const bf16x8*)(qp + 32);

    f32x4 sc[13];
#pragma unroll
    for (int nt = 0; nt < 13; ++nt) sc[nt] = zero4;
#pragma unroll
    for (int nt = 0; nt < 13; ++nt) {
      int key = nt * 16 + l;
      int rb = key * 128, sw = (key & 7) << 4, kb = g * 16;
      bf16x8 kb0 = *(const bf16x8*)((const unsigned char*)Ksh + rb + (kb ^ sw));
      bf16x8 kb1 = *(const bf16x8*)((const unsigned char*)Ksh + rb + ((kb + 64) ^ sw));
      sc[nt] = __builtin_amdgcn_mfma_f32_16x16x32_bf16(kb0, qa0, sc[nt], 0, 0, 0);
      sc[nt] = __builtin_amdgcn_mfma_f32_16x16x32_bf16(kb1, qa1, sc[nt], 0, 0, 0);
    }

    float mx = -1e30f;
#pragma unroll
    for (int nt = 0; nt < 13; ++nt)
#pragma unroll
      for (int r = 0; r < 4; ++r) {
        int key = nt * 16 + g * 4 + r;
        float s = sc[nt][r] * scale;
        bool ok = (key < 197 || qr == 197) && (key < SKV);
        s = ok ? s : -1e30f;
        sc[nt][r] = s;
        mx = fmaxf(mx, s);
      }
    mx = fmaxf(mx, __shfl_xor(mx, 16));
    mx = fmaxf(mx, __shfl_xor(mx, 32));
    float sum = 0.f;
#pragma unroll
    for (int nt = 0; nt < 13; ++nt)
#pragma unroll
      for (int r = 0; r < 4; ++r) {
        float p = __expf(sc[nt][r] - mx);
        sc[nt][r] = p;
        sum += p;
      }
    sum += __shfl_xor(sum, 16);
    sum += __shfl_xor(sum, 32);
    float inv = 1.0f / sum;

    unsigned pk0[13], pk1[13];
#pragma unroll
    for (int nt = 0; nt < 13; ++nt) {
      asm("v_cvt_pk_bf16_f32 %0, %1, %2" : "=v"(pk0[nt]) : "v"(sc[nt][0]), "v"(sc[nt][1]));
      asm("v_cvt_pk_bf16_f32 %0, %1, %2" : "=v"(pk1[nt]) : "v"(sc[nt][2]), "v"(sc[nt][3]));
    }

    f32x4 ctx[4];
#pragma unroll
    for (int dt = 0; dt < 4; ++dt) ctx[dt] = zero4;
#pragma unroll
    for (int c = 0; c < 7; ++c) {
      union { unsigned w[4]; bf16x8 v; } pa;
      if (c < 6) {
        int n0 = 2 * c, n1 = 2 * c + 1;
        unsigned a0 = (unsigned)__shfl((int)pk0[n0], srcA), b0 = (unsigned)__shfl((int)pk0[n1], srcA);
        unsigned a1 = (unsigned)__shfl((int)pk1[n0], srcA), b1 = (unsigned)__shfl((int)pk1[n1], srcA);
        unsigned a2 = (unsigned)__shfl((int)pk0[n0], srcB), b2 = (unsigned)__shfl((int)pk0[n1], srcB);
        unsigned a3 = (unsigned)__shfl((int)pk1[n0], srcB), b3 = (unsigned)__shfl((int)pk1[n1], srcB);
        pa.w[0] = hiHalf ? b0 : a0;
        pa.w[1] = hiHalf ? b1 : a1;
        pa.w[2] = hiHalf ? b2 : a2;
        pa.w[3] = hiHalf ? b3 : a3;
      } else {
        unsigned a0 = (unsigned)__shfl((int)pk0[12], srcA);
        unsigned a1 = (unsigned)__shfl((int)pk1[12], srcA);
        unsigned a2 = (unsigned)__shfl((int)pk0[12], srcB);
        unsigned a3 = (unsigned)__shfl((int)pk1[12], srcB);
        pa.w[0] = hiHalf ? 0u : a0;
        pa.w[1] = hiHalf ? 0u : a1;
        pa.w[2] = hiHalf ? 0u : a2;
        pa.w[3] = hiHalf ? 0u : a3;
      }
      int colb = c * 32 + g * 8;
      if (c == 6 && hiHalf) colb = 0;
#pragma unroll
      for (int dt = 0; dt < 4; ++dt) {
        bf16x8 vb = *(const bf16x8*)(VtB + vt_off(dt * 16 + l, colb));
        ctx[dt] = __builtin_amdgcn_mfma_f32_16x16x32_bf16(pa.v, vb, ctx[dt], 0, 0, 0);
      }
    }

    float invr[4];
#pragma unroll
    for (int r = 0; r < 4; ++r) invr[r] = __shfl(inv, g * 4 + r);
#pragma unroll
    for (int dt = 0; dt < 4; ++dt)
#pragma unroll
      for (int r = 0; r < 4; ++r) {
        int qo = qt * 16 + g * 4 + r;
        if (qo < SQ)
          out[(b * SQ + qo) * DM + h * 64 + dt * 16 + l] = ctx[dt][r] * invr[r];
      }
  }
}

extern "C" void kernel_launch(void* const* d_in, const int* in_sizes, int n_in,
                              void* d_out, int out_size, void* d_ws, size_t ws_size,
                              hipStream_t stream) {
  const float* hid = (const float*)d_in[0];
  const float* mem = (const float*)d_in[1];
  const float* Wq  = (const float*)d_in[2];
  const float* bq  = (const float*)d_in[3];
  const float* Wk  = (const float*)d_in[4];
  const float* bk  = (const float*)d_in[5];
  const float* Wv  = (const float*)d_in[6];
  const float* bv  = (const float*)d_in[7];
  float* out = (float*)d_out;

  unsigned short* xkv  = (unsigned short*)d_ws;
  unsigned short* wt   = xkv + NROWS * DM;
  unsigned short* cbuf = wt + 3 * DM * DM;

  k_conv_x<<<dim3(NROWS * DM / 8 / 256), 256, 0, stream>>>(hid, mem, xkv);
  k_conv_w<<<dim3(12, 12, 3), 256, 0, stream>>>(Wq, Wk, Wv, wt);
  k_gemm<<<dim3(468), 512, 0, stream>>>(xkv, wt, bq, bk, bv, cbuf);
  k_attn<<<dim3(NB * NH), 256, 0, stream>>>(cbuf, out);
}

// Round 7
// 104.596 us; speedup vs baseline: 1.3539x; 1.0043x over previous
//
#include <hip/hip_runtime.h>

typedef __attribute__((ext_vector_type(8))) short bf16x8;
typedef __attribute__((ext_vector_type(4))) float f32x4;
typedef __attribute__((ext_vector_type(4))) unsigned int u32x4;

#define NB 64
#define SQ 198
#define SKV 206
#define DM 768
#define NH 12
#define NROWS (NB * SKV)   // 13184
#define NCOL 2304          // Q | K | V columns

static __device__ __forceinline__ unsigned short f2b(float f) {
  union { float f; unsigned u; } v; v.f = f;
  unsigned r = v.u + 0x7FFFu + ((v.u >> 16) & 1u);
  return (unsigned short)(r >> 16);
}

typedef const __attribute__((address_space(1))) unsigned int g_u32;
typedef __attribute__((address_space(3))) unsigned int l_u32;
static __device__ __forceinline__ void gload_lds16(const void* g, void* l) {
  __builtin_amdgcn_global_load_lds((g_u32*)g, (l_u32*)l, 16, 0, 0);
}

// ---------- build bf16 Xkv[13184][768] ----------
__global__ __launch_bounds__(256) void k_conv_x(const float* __restrict__ hid,
                                                const float* __restrict__ mem,
                                                unsigned short* __restrict__ xkv) {
  int idx = (blockIdx.x * 256 + threadIdx.x) * 8;
  int r = idx / DM;
  int c = idx - r * DM;
  int b = r / SKV, s = r - b * SKV;
  const float* src = (s < SQ) ? (hid + (b * SQ + s) * DM + c)
                              : (mem + (s - SQ) * DM + c);
  float4 v0 = ((const float4*)src)[0];
  float4 v1 = ((const float4*)src)[1];
  unsigned w0 = f2b(v0.x) | ((unsigned)f2b(v0.y) << 16);
  unsigned w1 = f2b(v0.z) | ((unsigned)f2b(v0.w) << 16);
  unsigned w2 = f2b(v1.x) | ((unsigned)f2b(v1.y) << 16);
  unsigned w3 = f2b(v1.z) | ((unsigned)f2b(v1.w) << 16);
  u32x4 o = {w0, w1, w2, w3};
  *(u32x4*)(xkv + idx) = o;
}

// ---------- transpose W -> bf16 Wt[w][n][k] ----------
__global__ __launch_bounds__(256) void k_conv_w(const float* __restrict__ Wq,
                                                const float* __restrict__ Wk,
                                                const float* __restrict__ Wv,
                                                unsigned short* __restrict__ wt) {
  __shared__ float L[64][65];
  int w = blockIdx.z;
  int n0 = blockIdx.x * 64, k0 = blockIdx.y * 64;
  const float* W = (w == 0) ? Wq : (w == 1) ? Wk : Wv;
  int tid = threadIdx.x;
#pragma unroll
  for (int i = 0; i < 16; ++i) {
    int idx = i * 256 + tid;
    int lr = idx >> 6, lc = idx & 63;
    L[lr][lc] = W[(k0 + lr) * DM + n0 + lc];
  }
  __syncthreads();
  unsigned short* dst = wt + w * DM * DM;
#pragma unroll
  for (int o = 0; o < 2; ++o) {
    int gi = o * 256 + tid;
    int rn = gi >> 3, g = gi & 7;
    unsigned wrd[4];
#pragma unroll
    for (int jj = 0; jj < 4; ++jj) {
      float f0 = L[g * 8 + jj * 2 + 0][rn];
      float f1 = L[g * 8 + jj * 2 + 1][rn];
      wrd[jj] = f2b(f0) | ((unsigned)f2b(f1) << 16);
    }
    u32x4 o4 = {wrd[0], wrd[1], wrd[2], wrd[3]};
    *(u32x4*)(dst + (n0 + rn) * DM + k0 + g * 8) = o4;
  }
}

// ---------- fused QKV GEMM v4: 256x256, BK=32, 4-buf counted-vmcnt, 2-phase/tile ----------
// Swizzle: phys granule = logical ^ ((row>>1)&3). Readiness rule: every vmcnt(N)
// that opens a new buffer is IMMEDIATELY followed by s_barrier BEFORE any ds_read
// of that buffer (vmcnt is per-wave; readers consume other waves' staging).
__global__ __launch_bounds__(512, 2) void k_gemm(const unsigned short* __restrict__ xkv,
                                                 const unsigned short* __restrict__ wt,
                                                 const float* __restrict__ bq,
                                                 const float* __restrict__ bk,
                                                 const float* __restrict__ bv,
                                                 unsigned short* __restrict__ cout) {
  __shared__ __align__(16) unsigned char smem[131072];
  // bijective XCD swizzle (nwg=468: q=58, r=4)
  int o = blockIdx.x, xcd = o & 7, rest = o >> 3;
  int sid = (xcd < 4 ? xcd * 59 : 236 + (xcd - 4) * 58) + rest;
  int mtile = sid / 9, ntile = sid - mtile * 9;
  int row0 = mtile * 256, col0 = ntile * 256;
  int w = ntile / 3;
  int colw0 = (ntile - w * 3) * 256;
  int tid = threadIdx.x, lane = tid & 63, wid = tid >> 6;
  int wm = wid >> 2, wn = wid & 3;      // 2M x 4N waves
  int l = lane & 15, gq = lane >> 4;
  const unsigned short* wbase = wt + w * DM * DM;

  const unsigned short* aP0;
  const unsigned short* aP1;
  const unsigned short* bP0;
  const unsigned short* bP1;
  {
    int sr = tid >> 2, pg = tid & 3, sg = pg ^ ((sr >> 1) & 3);
    int ar0 = row0 + sr;       if (ar0 > NROWS - 1) ar0 = NROWS - 1;
    int ar1 = row0 + 128 + sr; if (ar1 > NROWS - 1) ar1 = NROWS - 1;
    aP0 = xkv + ar0 * DM + sg * 8;
    aP1 = xkv + ar1 * DM + sg * 8;
    bP0 = wbase + (colw0 + sr) * DM + sg * 8;
    bP1 = wbase + (colw0 + 128 + sr) * DM + sg * 8;
  }
  int ldsW = wid * 1024;                // wave-uniform LDS base (HW adds lane*16)

  f32x4 zero = {0.f, 0.f, 0.f, 0.f};
  f32x4 acc[8][4];
#pragma unroll
  for (int i = 0; i < 8; ++i)
#pragma unroll
    for (int j = 0; j < 4; ++j) acc[i][j] = zero;

  // prologue: stage tiles 0,1,2 (12 loads/thread)
#pragma unroll
  for (int p = 0; p < 3; ++p) {
    gload_lds16(aP0 + p * 32, smem + p * 16384 + ldsW);
    gload_lds16(aP1 + p * 32, smem + p * 16384 + 8192 + ldsW);
    gload_lds16(bP0 + p * 32, smem + 65536 + p * 16384 + ldsW);
    gload_lds16(bP1 + p * 32, smem + 65536 + p * 16384 + 8192 + ldsW);
  }
  asm volatile("s_waitcnt vmcnt(8)" ::: "memory");   // tile 0 landed (this wave)
  __builtin_amdgcn_s_barrier();                      // ... and for all waves

  int swx = (gq * 16) ^ (((l >> 1) & 3) << 4);
  int aRd = (wm * 128 + l) * 64 + swx;            // + mi*1024 + bufA off
  int bRd = (wn * 64 + l) * 64 + swx;             // + ni*1024 + bufB off

#pragma unroll 1
  for (int t = 0; t < 24; ++t) {
    int boA = (t & 3) * 16384;
    int boB = 65536 + boA;
    int io = ((t + 3) & 3) * 16384;
    int kI = (t + 3) * 32;
    bool st = (t < 21);
    // ---- phase 0: buf t is ready (end-of-previous-tile vmcnt+barrier) ----
    bf16x8 af[4], bfr[4];
#pragma unroll
    for (int mi = 0; mi < 4; ++mi) af[mi] = *(const bf16x8*)(smem + boA + aRd + mi * 1024);
#pragma unroll
    for (int ni = 0; ni < 4; ++ni) bfr[ni] = *(const bf16x8*)(smem + boB + bRd + ni * 1024);
    if (st) {
      gload_lds16(aP0 + kI, smem + io + ldsW);
      gload_lds16(aP1 + kI, smem + io + 8192 + ldsW);
    }
    __builtin_amdgcn_s_barrier();
    asm volatile("s_waitcnt lgkmcnt(0)" ::: "memory");
    __builtin_amdgcn_sched_barrier(0);
    __builtin_amdgcn_s_setprio(1);
#pragma unroll
    for (int mi = 0; mi < 4; ++mi)
#pragma unroll
      for (int ni = 0; ni < 4; ++ni)
        acc[mi][ni] = __builtin_amdgcn_mfma_f32_16x16x32_bf16(af[mi], bfr[ni], acc[mi][ni], 0, 0, 0);
    __builtin_amdgcn_s_setprio(0);
    __builtin_amdgcn_s_barrier();
    // ---- phase 1 ----
    bf16x8 ag[4];
#pragma unroll
    for (int mi = 0; mi < 4; ++mi) ag[mi] = *(const bf16x8*)(smem + boA + aRd + (4 + mi) * 1024);
    if (st) {
      gload_lds16(bP0 + kI, smem + 65536 + io + ldsW);
      gload_lds16(bP1 + kI, smem + 65536 + io + 8192 + ldsW);
    }
    __builtin_amdgcn_s_barrier();
    asm volatile("s_waitcnt lgkmcnt(0)" ::: "memory");
    __builtin_amdgcn_sched_barrier(0);
    __builtin_amdgcn_s_setprio(1);
#pragma unroll
    for (int mi = 0; mi < 4; ++mi)
#pragma unroll
      for (int ni = 0; ni < 4; ++ni)
        acc[4 + mi][ni] = __builtin_amdgcn_mfma_f32_16x16x32_bf16(ag[mi], bfr[ni], acc[4 + mi][ni], 0, 0, 0);
    __builtin_amdgcn_s_setprio(0);
    // ---- end-of-tile: open buffer for tile t+1 across ALL waves ----
    if (t < 21)       { asm volatile("s_waitcnt vmcnt(8)" ::: "memory"); }
    else if (t == 21) { asm volatile("s_waitcnt vmcnt(4)" ::: "memory"); }
    else if (t == 22) { asm volatile("s_waitcnt vmcnt(0)" ::: "memory"); }
    __builtin_amdgcn_s_barrier();
  }

  // epilogue: bias + bf16 C through LDS (row-major [256][512B], (row&7)<<4 XOR)
  const float* bias = (w == 0) ? bq : (w == 1) ? bk : bv;
  float bb[4];
#pragma unroll
  for (int ni = 0; ni < 4; ++ni) bb[ni] = bias[colw0 + wn * 64 + ni * 16 + l];

  __syncthreads();
#pragma unroll
  for (int mi = 0; mi < 8; ++mi)
#pragma unroll
    for (int ni = 0; ni < 4; ++ni)
#pragma unroll
      for (int rr = 0; rr < 4; ++rr) {
        int row = wm * 128 + mi * 16 + gq * 4 + rr;
        int col = wn * 64 + ni * 16 + l;
        *(unsigned short*)(smem + row * 512 + ((col * 2) ^ ((row & 7) << 4))) =
            f2b(acc[mi][ni][rr] + bb[ni]);
      }
  __syncthreads();
#pragma unroll
  for (int it = 0; it < 16; ++it) {
    int gi = it * 512 + tid;
    int row = gi >> 5, gran = gi & 31;
    if (row0 + row < NROWS) {
      u32x4 v = *(const u32x4*)(smem + row * 512 + ((gran * 16) ^ ((row & 7) << 4)));
      *(u32x4*)(cout + (row0 + row) * NCOL + col0 + gran * 8) = v;
    }
  }
}

// ---------- attention (unchanged): swapped QK^T, in-register P, 52KB LDS ----------
static __device__ __forceinline__ int vt_off(int row, int col) {
  return row * 416 + ((col * 2) ^ (((row >> 3) & 1) << 4));
}

__global__ __launch_bounds__(256, 3) void k_attn(const unsigned short* __restrict__ cqkv,
                                                 float* __restrict__ out) {
  __shared__ __align__(16) unsigned short Ksh[208 * 64];
  __shared__ __align__(16) unsigned char  VtB[64 * 416];
  int bh = blockIdx.x;
  int b = bh / NH, h = bh - b * NH;
  int tid = threadIdx.x, lane = tid & 63, wid = tid >> 6;
  int g = lane >> 4, l = lane & 15;
  const unsigned short* Cb = cqkv + (b * SKV) * NCOL + h * 64;

  if (tid < 64) *(unsigned*)(VtB + vt_off(tid, 206)) = 0u;
  for (int i = tid; i < 208 * 8; i += 256) {
    int row = i >> 3, gg = i & 7;
    int srow = (row < SKV) ? row : (SKV - 1);
    u32x4 v = *(const u32x4*)(Cb + srow * NCOL + 768 + gg * 8);
    *(u32x4*)((unsigned char*)Ksh + ((row * 128 + gg * 16) ^ ((row & 7) << 4))) = v;
  }
  for (int i = tid; i < 206 * 8; i += 256) {
    int key = i >> 3, gg = i & 7;
    u32x4 v = *(const u32x4*)(Cb + key * NCOL + 1536 + gg * 8);
    union { u32x4 v4; unsigned short e[8]; } u; u.v4 = v;
#pragma unroll
    for (int j = 0; j < 8; ++j)
      *(unsigned short*)(VtB + vt_off(gg * 8 + j, key)) = u.e[j];
  }
  __syncthreads();

  const float scale = 0.125f;
  f32x4 zero4 = {0.f, 0.f, 0.f, 0.f};
  int srcA = ((g & 1) << 5) + l;
  int srcB = srcA + 16;
  bool hiHalf = (g >= 2);

  for (int qt = wid; qt < 13; qt += 4) {
    int qr = qt * 16 + l;
    int qld = qr > 197 ? 197 : qr;
    const unsigned short* qp = Cb + qld * NCOL + g * 8;
    bf16x8 qa0 = *(const bf16x8*)qp;
    bf16x8 qa1 = *(const bf16x8*)(qp + 32);

    f32x4 sc[13];
#pragma unroll
    for (int nt = 0; nt < 13; ++nt) sc[nt] = zero4;
#pragma unroll
    for (int nt = 0; nt < 13; ++nt) {
      int key = nt * 16 + l;
      int rb = key * 128, sw = (key & 7) << 4, kb = g * 16;
      bf16x8 kb0 = *(const bf16x8*)((const unsigned char*)Ksh + rb + (kb ^ sw));
      bf16x8 kb1 = *(const bf16x8*)((const unsigned char*)Ksh + rb + ((kb + 64) ^ sw));
      sc[nt] = __builtin_amdgcn_mfma_f32_16x16x32_bf16(kb0, qa0, sc[nt], 0, 0, 0);
      sc[nt] = __builtin_amdgcn_mfma_f32_16x16x32_bf16(kb1, qa1, sc[nt], 0, 0, 0);
    }

    float mx = -1e30f;
#pragma unroll
    for (int nt = 0; nt < 13; ++nt)
#pragma unroll
      for (int r = 0; r < 4; ++r) {
        int key = nt * 16 + g * 4 + r;
        float s = sc[nt][r] * scale;
        bool ok = (key < 197 || qr == 197) && (key < SKV);
        s = ok ? s : -1e30f;
        sc[nt][r] = s;
        mx = fmaxf(mx, s);
      }
    mx = fmaxf(mx, __shfl_xor(mx, 16));
    mx = fmaxf(mx, __shfl_xor(mx, 32));
    float sum = 0.f;
#pragma unroll
    for (int nt = 0; nt < 13; ++nt)
#pragma unroll
      for (int r = 0; r < 4; ++r) {
        float p = __expf(sc[nt][r] - mx);
        sc[nt][r] = p;
        sum += p;
      }
    sum += __shfl_xor(sum, 16);
    sum += __shfl_xor(sum, 32);
    float inv = 1.0f / sum;

    unsigned pk0[13], pk1[13];
#pragma unroll
    for (int nt = 0; nt < 13; ++nt) {
      asm("v_cvt_pk_bf16_f32 %0, %1, %2" : "=v"(pk0[nt]) : "v"(sc[nt][0]), "v"(sc[nt][1]));
      asm("v_cvt_pk_bf16_f32 %0, %1, %2" : "=v"(pk1[nt]) : "v"(sc[nt][2]), "v"(sc[nt][3]));
    }

    f32x4 ctx[4];
#pragma unroll
    for (int dt = 0; dt < 4; ++dt) ctx[dt] = zero4;
#pragma unroll
    for (int c = 0; c < 7; ++c) {
      union { unsigned w[4]; bf16x8 v; } pa;
      if (c < 6) {
        int n0 = 2 * c, n1 = 2 * c + 1;
        unsigned a0 = (unsigned)__shfl((int)pk0[n0], srcA), b0 = (unsigned)__shfl((int)pk0[n1], srcA);
        unsigned a1 = (unsigned)__shfl((int)pk1[n0], srcA), b1 = (unsigned)__shfl((int)pk1[n1], srcA);
        unsigned a2 = (unsigned)__shfl((int)pk0[n0], srcB), b2 = (unsigned)__shfl((int)pk0[n1], srcB);
        unsigned a3 = (unsigned)__shfl((int)pk1[n0], srcB), b3 = (unsigned)__shfl((int)pk1[n1], srcB);
        pa.w[0] = hiHalf ? b0 : a0;
        pa.w[1] = hiHalf ? b1 : a1;
        pa.w[2] = hiHalf ? b2 : a2;
        pa.w[3] = hiHalf ? b3 : a3;
      } else {
        unsigned a0 = (unsigned)__shfl((int)pk0[12], srcA);
        unsigned a1 = (unsigned)__shfl((int)pk1[12], srcA);
        unsigned a2 = (unsigned)__shfl((int)pk0[12], srcB);
        unsigned a3 = (unsigned)__shfl((int)pk1[12], srcB);
        pa.w[0] = hiHalf ? 0u : a0;
        pa.w[1] = hiHalf ? 0u : a1;
        pa.w[2] = hiHalf ? 0u : a2;
        pa.w[3] = hiHalf ? 0u : a3;
      }
      int colb = c * 32 + g * 8;
      if (c == 6 && hiHalf) colb = 0;
#pragma unroll
      for (int dt = 0; dt < 4; ++dt) {
        bf16x8 vb = *(const bf16x8*)(VtB + vt_off(dt * 16 + l, colb));
        ctx[dt] = __builtin_amdgcn_mfma_f32_16x16x32_bf16(pa.v, vb, ctx[dt], 0, 0, 0);
      }
    }

    float invr[4];
#pragma unroll
    for (int r = 0; r < 4; ++r) invr[r] = __shfl(inv, g * 4 + r);
#pragma unroll
    for (int dt = 0; dt < 4; ++dt)
#pragma unroll
      for (int r = 0; r < 4; ++r) {
        int qo = qt * 16 + g * 4 + r;
        if (qo < SQ)
          out[(b * SQ + qo) * DM + h * 64 + dt * 16 + l] = ctx[dt][r] * invr[r];
      }
  }
}

extern "C" void kernel_launch(void* const* d_in, const int* in_sizes, int n_in,
                              void* d_out, int out_size, void* d_ws, size_t ws_size,
                              hipStream_t stream) {
  const float* hid = (const float*)d_in[0];
  const float* mem = (const float*)d_in[1];
  const float* Wq  = (const float*)d_in[2];
  const float* bq  = (const float*)d_in[3];
  const float* Wk  = (const float*)d_in[4];
  const float* bk  = (const float*)d_in[5];
  const float* Wv  = (const float*)d_in[6];
  const float* bv  = (const float*)d_in[7];
  float* out = (float*)d_out;

  unsigned short* xkv  = (unsigned short*)d_ws;
  unsigned short* wt   = xkv + NROWS * DM;
  unsigned short* cbuf = wt + 3 * DM * DM;

  k_conv_x<<<dim3(NROWS * DM / 8 / 256), 256, 0, stream>>>(hid, mem, xkv);
  k_conv_w<<<dim3(12, 12, 3), 256, 0, stream>>>(Wq, Wk, Wv, wt);
  k_gemm<<<dim3(468), 512, 0, stream>>>(xkv, wt, bq, bk, bv, cbuf);
  k_attn<<<dim3(NB * NH), 256, 0, stream>>>(cbuf, out);
}

// Round 8
// 102.974 us; speedup vs baseline: 1.3752x; 1.0158x over previous
//
#include <hip/hip_runtime.h>

typedef __attribute__((ext_vector_type(8))) short bf16x8;
typedef __attribute__((ext_vector_type(4))) float f32x4;
typedef __attribute__((ext_vector_type(4))) unsigned int u32x4;

#define NB 64
#define SQ 198
#define SKV 206
#define DM 768
#define NH 12
#define NROWS (NB * SKV)   // 13184
#define NCOL 2304          // Q | K | V columns

static __device__ __forceinline__ unsigned short f2b(float f) {
  union { float f; unsigned u; } v; v.f = f;
  unsigned r = v.u + 0x7FFFu + ((v.u >> 16) & 1u);
  return (unsigned short)(r >> 16);
}

typedef const __attribute__((address_space(1))) unsigned int g_u32;
typedef __attribute__((address_space(3))) unsigned int l_u32;
static __device__ __forceinline__ void gload_lds16(const void* g, void* l) {
  __builtin_amdgcn_global_load_lds((g_u32*)g, (l_u32*)l, 16, 0, 0);
}

// ---------- build bf16 Xkv[13184][768] ----------
__global__ __launch_bounds__(256) void k_conv_x(const float* __restrict__ hid,
                                                const float* __restrict__ mem,
                                                unsigned short* __restrict__ xkv) {
  int idx = (blockIdx.x * 256 + threadIdx.x) * 8;
  int r = idx / DM;
  int c = idx - r * DM;
  int b = r / SKV, s = r - b * SKV;
  const float* src = (s < SQ) ? (hid + (b * SQ + s) * DM + c)
                              : (mem + (s - SQ) * DM + c);
  float4 v0 = ((const float4*)src)[0];
  float4 v1 = ((const float4*)src)[1];
  unsigned w0 = f2b(v0.x) | ((unsigned)f2b(v0.y) << 16);
  unsigned w1 = f2b(v0.z) | ((unsigned)f2b(v0.w) << 16);
  unsigned w2 = f2b(v1.x) | ((unsigned)f2b(v1.y) << 16);
  unsigned w3 = f2b(v1.z) | ((unsigned)f2b(v1.w) << 16);
  u32x4 o = {w0, w1, w2, w3};
  *(u32x4*)(xkv + idx) = o;
}

// ---------- transpose W -> bf16 Wt[w][n][k] ----------
__global__ __launch_bounds__(256) void k_conv_w(const float* __restrict__ Wq,
                                                const float* __restrict__ Wk,
                                                const float* __restrict__ Wv,
                                                unsigned short* __restrict__ wt) {
  __shared__ float L[64][65];
  int w = blockIdx.z;
  int n0 = blockIdx.x * 64, k0 = blockIdx.y * 64;
  const float* W = (w == 0) ? Wq : (w == 1) ? Wk : Wv;
  int tid = threadIdx.x;
#pragma unroll
  for (int i = 0; i < 16; ++i) {
    int idx = i * 256 + tid;
    int lr = idx >> 6, lc = idx & 63;
    L[lr][lc] = W[(k0 + lr) * DM + n0 + lc];
  }
  __syncthreads();
  unsigned short* dst = wt + w * DM * DM;
#pragma unroll
  for (int o = 0; o < 2; ++o) {
    int gi = o * 256 + tid;
    int rn = gi >> 3, g = gi & 7;
    unsigned wrd[4];
#pragma unroll
    for (int jj = 0; jj < 4; ++jj) {
      float f0 = L[g * 8 + jj * 2 + 0][rn];
      float f1 = L[g * 8 + jj * 2 + 1][rn];
      wrd[jj] = f2b(f0) | ((unsigned)f2b(f1) << 16);
    }
    u32x4 o4 = {wrd[0], wrd[1], wrd[2], wrd[3]};
    *(u32x4*)(dst + (n0 + rn) * DM + k0 + g * 8) = o4;
  }
}

// ---------- fused QKV GEMM v5: 128x256 tile, BK=32, 3-buf, 2 blocks/CU ----------
// Occupancy-first: per-wave 64x64 (acc[4][4] = 64 VGPR) -> 4 waves/SIMD.
// LDS 3 x 24KB: per buf A[0,8K) B[8K,24K). Granule swizzle phys = g ^ ((row>>1)&3)
// (zero-conflict, verified R7). One barrier per K-tile; counted vmcnt(3).
__global__ __launch_bounds__(512, 4) void k_gemm(const unsigned short* __restrict__ xkv,
                                                 const unsigned short* __restrict__ wt,
                                                 const float* __restrict__ bq,
                                                 const float* __restrict__ bk,
                                                 const float* __restrict__ bv,
                                                 unsigned short* __restrict__ cout) {
  __shared__ __align__(16) unsigned char smem[73728];
  // bijective XCD swizzle (nwg=927: q=115, r=7)
  int o = blockIdx.x, xcd = o & 7, rest = o >> 3;
  int sid = (xcd < 7 ? xcd * 116 : 812) + (xcd < 7 ? 0 : (xcd - 7) * 115) + rest;
  int mtile = sid / 9, ntile = sid - mtile * 9;
  int row0 = mtile * 128, col0 = ntile * 256;
  int w = ntile / 3;
  int colw0 = (ntile - w * 3) * 256;
  int tid = threadIdx.x, lane = tid & 63, wid = tid >> 6;
  int wm = wid >> 2, wn = wid & 3;      // 2M x 4N waves, each 64x64 out
  int l = lane & 15, gq = lane >> 4;
  const unsigned short* wbase = wt + w * DM * DM;

  // staging: slot tid -> row sr=tid>>2, phys granule pg=tid&3, src granule pg^((sr>>1)&3)
  const unsigned short* aP;
  const unsigned short* bP0;
  const unsigned short* bP1;
  {
    int sr = tid >> 2, pg = tid & 3, sg = pg ^ ((sr >> 1) & 3);
    aP  = xkv   + (row0 + sr) * DM + sg * 8;            // M=103*128 exact, no clamp
    bP0 = wbase + (colw0 + sr) * DM + sg * 8;
    bP1 = wbase + (colw0 + 128 + sr) * DM + sg * 8;
  }
  int ldsW = wid * 1024;                // wave-uniform LDS base (HW adds lane*16)

  f32x4 zero = {0.f, 0.f, 0.f, 0.f};
  f32x4 acc[4][4];
#pragma unroll
  for (int i = 0; i < 4; ++i)
#pragma unroll
    for (int j = 0; j < 4; ++j) acc[i][j] = zero;

  // prologue: stage tiles 0,1 (6 loads/thread)
#pragma unroll
  for (int p = 0; p < 2; ++p) {
    int bo = p * 24576;
    gload_lds16(aP  + p * 32, smem + bo + ldsW);
    gload_lds16(bP0 + p * 32, smem + bo + 8192 + ldsW);
    gload_lds16(bP1 + p * 32, smem + bo + 16384 + ldsW);
  }
  asm volatile("s_waitcnt vmcnt(3)" ::: "memory");   // tile 0 landed (this wave)
  __builtin_amdgcn_s_barrier();                      // ... and for all waves

  int swx = (gq * 16) ^ (((l >> 1) & 3) << 4);
  int aRd = (wm * 64 + l) * 64 + swx;            // + mi*1024 + buf off
  int bRd = 8192 + (wn * 64 + l) * 64 + swx;     // + ni*1024 + buf off

  int q = 0;          // t % 3
  int qn = 2;         // (t+2) % 3
#pragma unroll 1
  for (int t = 0; t < 24; ++t) {
    const unsigned char* bp = smem + q * 24576;
    // issue stage of tile t+2 FIRST (hides under this tile's compute)
    if (t < 22) {
      unsigned char* ip = smem + qn * 24576;
      int kI = (t + 2) * 32;
      gload_lds16(aP  + kI, ip + ldsW);
      gload_lds16(bP0 + kI, ip + 8192 + ldsW);
      gload_lds16(bP1 + kI, ip + 16384 + ldsW);
    }
    bf16x8 a[4], b[4];
#pragma unroll
    for (int mi = 0; mi < 4; ++mi) a[mi] = *(const bf16x8*)(bp + aRd + mi * 1024);
#pragma unroll
    for (int ni = 0; ni < 4; ++ni) b[ni] = *(const bf16x8*)(bp + bRd + ni * 1024);
    __builtin_amdgcn_s_setprio(1);
#pragma unroll
    for (int mi = 0; mi < 4; ++mi)
#pragma unroll
      for (int ni = 0; ni < 4; ++ni)
        acc[mi][ni] = __builtin_amdgcn_mfma_f32_16x16x32_bf16(a[mi], b[ni], acc[mi][ni], 0, 0, 0);
    __builtin_amdgcn_s_setprio(0);
    // open buffer for tile t+1 across all waves (never full drain until t=22)
    if (t < 22)       { asm volatile("s_waitcnt vmcnt(3)" ::: "memory"); }
    else if (t == 22) { asm volatile("s_waitcnt vmcnt(0)" ::: "memory"); }
    __builtin_amdgcn_s_barrier();
    q = (q == 2) ? 0 : q + 1;
    qn = (qn == 2) ? 0 : qn + 1;
  }

  // epilogue: bias + bf16 C through LDS (128 rows x 512B, (row&7)<<4 XOR)
  const float* bias = (w == 0) ? bq : (w == 1) ? bk : bv;
  float bb[4];
#pragma unroll
  for (int ni = 0; ni < 4; ++ni) bb[ni] = bias[colw0 + wn * 64 + ni * 16 + l];

  __syncthreads();
#pragma unroll
  for (int mi = 0; mi < 4; ++mi)
#pragma unroll
    for (int ni = 0; ni < 4; ++ni)
#pragma unroll
      for (int rr = 0; rr < 4; ++rr) {
        int row = wm * 64 + mi * 16 + gq * 4 + rr;
        int col = wn * 64 + ni * 16 + l;
        *(unsigned short*)(smem + row * 512 + ((col * 2) ^ ((row & 7) << 4))) =
            f2b(acc[mi][ni][rr] + bb[ni]);
      }
  __syncthreads();
#pragma unroll
  for (int it = 0; it < 8; ++it) {
    int gi = it * 512 + tid;
    int row = gi >> 5, gran = gi & 31;
    u32x4 v = *(const u32x4*)(smem + row * 512 + ((gran * 16) ^ ((row & 7) << 4)));
    *(u32x4*)(cout + (row0 + row) * NCOL + col0 + gran * 8) = v;
  }
}

// ---------- attention (unchanged): swapped QK^T, in-register P, 52KB LDS ----------
static __device__ __forceinline__ int vt_off(int row, int col) {
  return row * 416 + ((col * 2) ^ (((row >> 3) & 1) << 4));
}

__global__ __launch_bounds__(256, 3) void k_attn(const unsigned short* __restrict__ cqkv,
                                                 float* __restrict__ out) {
  __shared__ __align__(16) unsigned short Ksh[208 * 64];
  __shared__ __align__(16) unsigned char  VtB[64 * 416];
  int bh = blockIdx.x;
  int b = bh / NH, h = bh - b * NH;
  int tid = threadIdx.x, lane = tid & 63, wid = tid >> 6;
  int g = lane >> 4, l = lane & 15;
  const unsigned short* Cb = cqkv + (b * SKV) * NCOL + h * 64;

  if (tid < 64) *(unsigned*)(VtB + vt_off(tid, 206)) = 0u;
  for (int i = tid; i < 208 * 8; i += 256) {
    int row = i >> 3, gg = i & 7;
    int srow = (row < SKV) ? row : (SKV - 1);
    u32x4 v = *(const u32x4*)(Cb + srow * NCOL + 768 + gg * 8);
    *(u32x4*)((unsigned char*)Ksh + ((row * 128 + gg * 16) ^ ((row & 7) << 4))) = v;
  }
  for (int i = tid; i < 206 * 8; i += 256) {
    int key = i >> 3, gg = i & 7;
    u32x4 v = *(const u32x4*)(Cb + key * NCOL + 1536 + gg * 8);
    union { u32x4 v4; unsigned short e[8]; } u; u.v4 = v;
#pragma unroll
    for (int j = 0; j < 8; ++j)
      *(unsigned short*)(VtB + vt_off(gg * 8 + j, key)) = u.e[j];
  }
  __syncthreads();

  const float scale = 0.125f;
  f32x4 zero4 = {0.f, 0.f, 0.f, 0.f};
  int srcA = ((g & 1) << 5) + l;
  int srcB = srcA + 16;
  bool hiHalf = (g >= 2);

  for (int qt = wid; qt < 13; qt += 4) {
    int qr = qt * 16 + l;
    int qld = qr > 197 ? 197 : qr;
    const unsigned short* qp = Cb + qld * NCOL + g * 8;
    bf16x8 qa0 = *(const bf16x8*)qp;
    bf16x8 qa1 = *(const bf16x8*)(qp + 32);

    f32x4 sc[13];
#pragma unroll
    for (int nt = 0; nt < 13; ++nt) sc[nt] = zero4;
#pragma unroll
    for (int nt = 0; nt < 13; ++nt) {
      int key = nt * 16 + l;
      int rb = key * 128, sw = (key & 7) << 4, kb = g * 16;
      bf16x8 kb0 = *(const bf16x8*)((const unsigned char*)Ksh + rb + (kb ^ sw));
      bf16x8 kb1 = *(const bf16x8*)((const unsigned char*)Ksh + rb + ((kb + 64) ^ sw));
      sc[nt] = __builtin_amdgcn_mfma_f32_16x16x32_bf16(kb0, qa0, sc[nt], 0, 0, 0);
      sc[nt] = __builtin_amdgcn_mfma_f32_16x16x32_bf16(kb1, qa1, sc[nt], 0, 0, 0);
    }

    float mx = -1e30f;
#pragma unroll
    for (int nt = 0; nt < 13; ++nt)
#pragma unroll
      for (int r = 0; r < 4; ++r) {
        int key = nt * 16 + g * 4 + r;
        float s = sc[nt][r] * scale;
        bool ok = (key < 197 || qr == 197) && (key < SKV);
        s = ok ? s : -1e30f;
        sc[nt][r] = s;
        mx = fmaxf(mx, s);
      }
    mx = fmaxf(mx, __shfl_xor(mx, 16));
    mx = fmaxf(mx, __shfl_xor(mx, 32));
    float sum = 0.f;
#pragma unroll
    for (int nt = 0; nt < 13; ++nt)
#pragma unroll
      for (int r = 0; r < 4; ++r) {
        float p = __expf(sc[nt][r] - mx);
        sc[nt][r] = p;
        sum += p;
      }
    sum += __shfl_xor(sum, 16);
    sum += __shfl_xor(sum, 32);
    float inv = 1.0f / sum;

    unsigned pk0[13], pk1[13];
#pragma unroll
    for (int nt = 0; nt < 13; ++nt) {
      asm("v_cvt_pk_bf16_f32 %0, %1, %2" : "=v"(pk0[nt]) : "v"(sc[nt][0]), "v"(sc[nt][1]));
      asm("v_cvt_pk_bf16_f32 %0, %1, %2" : "=v"(pk1[nt]) : "v"(sc[nt][2]), "v"(sc[nt][3]));
    }

    f32x4 ctx[4];
#pragma unroll
    for (int dt = 0; dt < 4; ++dt) ctx[dt] = zero4;
#pragma unroll
    for (int c = 0; c < 7; ++c) {
      union { unsigned w[4]; bf16x8 v; } pa;
      if (c < 6) {
        int n0 = 2 * c, n1 = 2 * c + 1;
        unsigned a0 = (unsigned)__shfl((int)pk0[n0], srcA), b0 = (unsigned)__shfl((int)pk0[n1], srcA);
        unsigned a1 = (unsigned)__shfl((int)pk1[n0], srcA), b1 = (unsigned)__shfl((int)pk1[n1], srcA);
        unsigned a2 = (unsigned)__shfl((int)pk0[n0], srcB), b2 = (unsigned)__shfl((int)pk0[n1], srcB);
        unsigned a3 = (unsigned)__shfl((int)pk1[n0], srcB), b3 = (unsigned)__shfl((int)pk1[n1], srcB);
        pa.w[0] = hiHalf ? b0 : a0;
        pa.w[1] = hiHalf ? b1 : a1;
        pa.w[2] = hiHalf ? b2 : a2;
        pa.w[3] = hiHalf ? b3 : a3;
      } else {
        unsigned a0 = (unsigned)__shfl((int)pk0[12], srcA);
        unsigned a1 = (unsigned)__shfl((int)pk1[12], srcA);
        unsigned a2 = (unsigned)__shfl((int)pk0[12], srcB);
        unsigned a3 = (unsigned)__shfl((int)pk1[12], srcB);
        pa.w[0] = hiHalf ? 0u : a0;
        pa.w[1] = hiHalf ? 0u : a1;
        pa.w[2] = hiHalf ? 0u : a2;
        pa.w[3] = hiHalf ? 0u : a3;
      }
      int colb = c * 32 + g * 8;
      if (c == 6 && hiHalf) colb = 0;
#pragma unroll
      for (int dt = 0; dt < 4; ++dt) {
        bf16x8 vb = *(const bf16x8*)(VtB + vt_off(dt * 16 + l, colb));
        ctx[dt] = __builtin_amdgcn_mfma_f32_16x16x32_bf16(pa.v, vb, ctx[dt], 0, 0, 0);
      }
    }

    float invr[4];
#pragma unroll
    for (int r = 0; r < 4; ++r) invr[r] = __shfl(inv, g * 4 + r);
#pragma unroll
    for (int dt = 0; dt < 4; ++dt)
#pragma unroll
      for (int r = 0; r < 4; ++r) {
        int qo = qt * 16 + g * 4 + r;
        if (qo < SQ)
          out[(b * SQ + qo) * DM + h * 64 + dt * 16 + l] = ctx[dt][r] * invr[r];
      }
  }
}

extern "C" void kernel_launch(void* const* d_in, const int* in_sizes, int n_in,
                              void* d_out, int out_size, void* d_ws, size_t ws_size,
                              hipStream_t stream) {
  const float* hid = (const float*)d_in[0];
  const float* mem = (const float*)d_in[1];
  const float* Wq  = (const float*)d_in[2];
  const float* bq  = (const float*)d_in[3];
  const float* Wk  = (const float*)d_in[4];
  const float* bk  = (const float*)d_in[5];
  const float* Wv  = (const float*)d_in[6];
  const float* bv  = (const float*)d_in[7];
  float* out = (float*)d_out;

  unsigned short* xkv  = (unsigned short*)d_ws;
  unsigned short* wt   = xkv + NROWS * DM;
  unsigned short* cbuf = wt + 3 * DM * DM;

  k_conv_x<<<dim3(NROWS * DM / 8 / 256), 256, 0, stream>>>(hid, mem, xkv);
  k_conv_w<<<dim3(12, 12, 3), 256, 0, stream>>>(Wq, Wk, Wv, wt);
  k_gemm<<<dim3(927), 512, 0, stream>>>(xkv, wt, bq, bk, bv, cbuf);
  k_attn<<<dim3(NB * NH), 256, 0, stream>>>(cbuf, out);
}